// Round 1
// baseline (550.812 us; speedup 1.0000x reference)
//
#include <hip/hip_runtime.h>

typedef __attribute__((ext_vector_type(8))) short short8;
typedef __attribute__((ext_vector_type(4))) short short4v;
typedef __attribute__((ext_vector_type(4))) float f32x4;

#define DEVI __device__ __forceinline__

// fp32 -> bf16 round-to-nearest-even
DEVI unsigned short f2bf(float x) {
  unsigned u = __builtin_bit_cast(unsigned, x);
  u += 0x7fff + ((u >> 16) & 1u);
  return (unsigned short)(u >> 16);
}

// ---------------------------------------------------------------------------
// Projection GEMM: C[m,n] = sum_k A[m,k] * W[n,k]   (W is (out,in) = B^T form)
// 128x128 tile, BK=32, 256 threads (4 waves, 2x2 of 64x64), reg-staged
// fp32->bf16 conversion into padded LDS (stride 40 shorts = 80B, 16B-aligned).
// MODE 0: out_bf16[m*ldo+n] = bf16((acc + bias[n]) * scale)
// MODE 2: atomicAdd(out_f32[m*ldo+n], acc)   (split-K partials, no bias)
// ---------------------------------------------------------------------------
template <int MODE>
DEVI void proj_body(const float* __restrict__ A, const float* __restrict__ W,
                    const float* __restrict__ bias, void* __restrict__ outp,
                    int M, int K, int ldo, float scale,
                    int bm, int bn, int kbeg, int kend) {
  __shared__ unsigned short sA[128][40];
  __shared__ unsigned short sB[128][40];
  const int tid  = threadIdx.x;
  const int lane = tid & 63, wid = tid >> 6;
  const int wr = (wid >> 1) * 64, wc = (wid & 1) * 64;
  const int m0 = bm * 128, n0 = bn * 128;
  const int srow = tid >> 3;            // 0..31 (+ p*32)
  const int scol = (tid & 7) * 4;       // 0..28
  const int lr = lane & 15, lk = (lane >> 4) * 8;

  f32x4 acc[4][4];
#pragma unroll
  for (int i = 0; i < 4; ++i)
#pragma unroll
    for (int j = 0; j < 4; ++j) acc[i][j] = (f32x4){0.f, 0.f, 0.f, 0.f};

  for (int k0 = kbeg; k0 < kend; k0 += 32) {
#pragma unroll
    for (int p = 0; p < 4; ++p) {
      const int row = p * 32 + srow;
      {  // A tile (guard rows >= M -> zeros)
        const int rg = m0 + row;
        f32x4 t = (rg < M) ? *(const f32x4*)(A + (size_t)rg * K + k0 + scol)
                           : (f32x4){0.f, 0.f, 0.f, 0.f};
        short4v s;
#pragma unroll
        for (int j = 0; j < 4; ++j) s[j] = (short)f2bf(t[j]);
        *(short4v*)&sA[row][scol] = s;
      }
      {  // W tile (N % 128 == 0 always)
        f32x4 t = *(const f32x4*)(W + (size_t)(n0 + row) * K + k0 + scol);
        short4v s;
#pragma unroll
        for (int j = 0; j < 4; ++j) s[j] = (short)f2bf(t[j]);
        *(short4v*)&sB[row][scol] = s;
      }
    }
    __syncthreads();
    short8 af[4], bfr[4];
#pragma unroll
    for (int i = 0; i < 4; ++i) af[i]  = *(const short8*)&sA[wr + i * 16 + lr][lk];
#pragma unroll
    for (int j = 0; j < 4; ++j) bfr[j] = *(const short8*)&sB[wc + j * 16 + lr][lk];
#pragma unroll
    for (int i = 0; i < 4; ++i)
#pragma unroll
      for (int j = 0; j < 4; ++j)
        acc[i][j] = __builtin_amdgcn_mfma_f32_16x16x32_bf16(af[i], bfr[j], acc[i][j], 0, 0, 0);
    __syncthreads();
  }

  // C-write. C/D layout: col = lane&15, row = (lane>>4)*4 + r  [m89-verified]
#pragma unroll
  for (int i = 0; i < 4; ++i) {
#pragma unroll
    for (int j = 0; j < 4; ++j) {
      const int n  = n0 + wc + j * 16 + lr;
      const int mb = m0 + wr + i * 16 + (lane >> 4) * 4;
      if (MODE == 0) {
        const float bv = bias[n];
        unsigned short* out = (unsigned short*)outp;
#pragma unroll
        for (int r = 0; r < 4; ++r)
          out[(size_t)(mb + r) * ldo + n] = f2bf((acc[i][j][r] + bv) * scale);
      } else {
        float* out = (float*)outp;
#pragma unroll
        for (int r = 0; r < 4; ++r)
          atomicAdd(&out[(size_t)(mb + r) * ldo + n], acc[i][j][r]);
      }
    }
  }
}

// Q projection: (8192x768) @ Wq^T + bq, scaled by 1/8 (folded attention scale)
__global__ __launch_bounds__(256) void qproj_kernel(const float* __restrict__ target,
                                                    const float* __restrict__ Wq,
                                                    const float* __restrict__ bq,
                                                    unsigned short* __restrict__ qb) {
  proj_body<0>(target, Wq, bq, qb, 8192, 768, 768, 0.125f, blockIdx.x, blockIdx.y, 0, 768);
}

// K/V projections, split-K x4: z = kv*4 + ksplit. fp32 atomic partials.
__global__ __launch_bounds__(256) void kvproj_kernel(const float* __restrict__ source,
                                                     const float* __restrict__ value,
                                                     const float* __restrict__ Wk,
                                                     const float* __restrict__ Wv,
                                                     float* __restrict__ kacc,
                                                     float* __restrict__ vacc) {
  const int kv = blockIdx.z >> 2, ks = blockIdx.z & 3;
  const float* A = kv ? value : source;
  const float* W = kv ? Wv : Wk;
  float* out = kv ? vacc : kacc;
  proj_body<2>(A, W, nullptr, out, 1000, 4096, 768, 1.0f,
               blockIdx.x, blockIdx.y, ks * 1024, ks * 1024 + 1024);
}

// finalize: z=0  kb[s][n]   = bf16(kacc + bk)          (1024x768)
//           z=1  vtb[n][s]  = bf16(vacc^T + bv)        (768x1024, transposed)
__global__ __launch_bounds__(256) void finalize_kv(const float* __restrict__ kacc,
                                                   const float* __restrict__ vacc,
                                                   const float* __restrict__ bk,
                                                   const float* __restrict__ bv,
                                                   unsigned short* __restrict__ kb,
                                                   unsigned short* __restrict__ vtb) {
  if (blockIdx.z == 0) {
    const int i = (blockIdx.x * 256 + threadIdx.x) * 8;  // < 786432
    const int col = i % 768;
    short8 p;
#pragma unroll
    for (int j = 0; j < 8; ++j) p[j] = (short)f2bf(kacc[i + j] + bk[col + j]);
    *(short8*)&kb[i] = p;
  } else {
    const int idx = blockIdx.x * 256 + threadIdx.x;      // < 98304
    const int n = idx >> 7;
    const int s0 = (idx & 127) * 8;
    const float bvn = bv[n];
    short8 p;
#pragma unroll
    for (int j = 0; j < 8; ++j) p[j] = (short)f2bf(vacc[(size_t)(s0 + j) * 768 + n] + bvn);
    *(short8*)&vtb[(size_t)n * 1024 + s0] = p;
  }
}

// ---------------------------------------------------------------------------
// Flash cross-attention. Grid (L/128, B*H). 4 waves; wave w owns 32 q-rows.
// KV-tile = 64. sK[s][e], sV[e][s] (V pre-transposed), sP per-wave P buffer.
// Online softmax in MFMA C-layout; 16-lane shfl_xor row reduction.
// ---------------------------------------------------------------------------
__global__ __launch_bounds__(256) void attn_kernel(const unsigned short* __restrict__ q,
                                                   const unsigned short* __restrict__ k,
                                                   const unsigned short* __restrict__ vt,
                                                   unsigned short* __restrict__ rep) {
  __shared__ unsigned short sK[64][72];
  __shared__ unsigned short sV[64][72];
  __shared__ unsigned short sP[128][72];

  const int tid = threadIdx.x;
  const int lane = tid & 63, w = tid >> 6;
  const int q0 = blockIdx.x * 128;
  const int b = blockIdx.y / 12, h = blockIdx.y % 12;
  const int lr = lane & 15, lk = (lane >> 4) * 8;
  const int qrow_base = b * 1024 + q0 + w * 32;

  // Q fragments live in registers for the whole block
  short8 qf[2][2];
#pragma unroll
  for (int fm = 0; fm < 2; ++fm)
#pragma unroll
    for (int kk = 0; kk < 2; ++kk)
      qf[fm][kk] = *(const short8*)&q[(size_t)(qrow_base + fm * 16 + lr) * 768 + h * 64 + kk * 32 + lk];

  float m_run[2][4], l_run[2][4];
  f32x4 o[2][4];
#pragma unroll
  for (int fm = 0; fm < 2; ++fm)
#pragma unroll
    for (int r = 0; r < 4; ++r) {
      m_run[fm][r] = -1e30f;
      l_run[fm][r] = 0.f;
    }
#pragma unroll
  for (int fm = 0; fm < 2; ++fm)
#pragma unroll
    for (int je = 0; je < 4; ++je) o[fm][je] = (f32x4){0.f, 0.f, 0.f, 0.f};

  const int strow = tid >> 2;           // 0..63
  const int stc = (tid & 3) * 16;       // 0,16,32,48

  for (int t = 0; t < 16; ++t) {
    const int s0 = t * 64;
    __syncthreads();
    {  // stage K tile [s][e] and V^T tile [e][s]
      const unsigned short* ks = &k[(size_t)(s0 + strow) * 768 + h * 64 + stc];
      *(short8*)&sK[strow][stc]     = *(const short8*)ks;
      *(short8*)&sK[strow][stc + 8] = *(const short8*)(ks + 8);
      const unsigned short* vs = &vt[(size_t)(h * 64 + strow) * 1024 + s0 + stc];
      *(short8*)&sV[strow][stc]     = *(const short8*)vs;
      *(short8*)&sV[strow][stc + 8] = *(const short8*)(vs + 8);
    }
    __syncthreads();

    // QK^T: scores 32(q) x 64(s) per wave
    f32x4 sc_acc[2][4];
#pragma unroll
    for (int fm = 0; fm < 2; ++fm)
#pragma unroll
      for (int j = 0; j < 4; ++j) sc_acc[fm][j] = (f32x4){0.f, 0.f, 0.f, 0.f};
    short8 kf[4][2];
#pragma unroll
    for (int j = 0; j < 4; ++j)
#pragma unroll
      for (int kk = 0; kk < 2; ++kk)
        kf[j][kk] = *(const short8*)&sK[j * 16 + lr][kk * 32 + lk];
#pragma unroll
    for (int fm = 0; fm < 2; ++fm)
#pragma unroll
      for (int j = 0; j < 4; ++j)
#pragma unroll
        for (int kk = 0; kk < 2; ++kk)
          sc_acc[fm][j] = __builtin_amdgcn_mfma_f32_16x16x32_bf16(qf[fm][kk], kf[j][kk], sc_acc[fm][j], 0, 0, 0);

    // tail mask (s >= 1000) — only last tile
    if (s0 + 64 > 1000) {
#pragma unroll
      for (int j = 0; j < 4; ++j)
        if (s0 + j * 16 + lr >= 1000) {
#pragma unroll
          for (int fm = 0; fm < 2; ++fm)
#pragma unroll
            for (int r = 0; r < 4; ++r) sc_acc[fm][j][r] = -1e30f;
        }
    }

    // online softmax (rows live in (lane>>4, r); 16-lane groups share a row)
#pragma unroll
    for (int fm = 0; fm < 2; ++fm) {
#pragma unroll
      for (int r = 0; r < 4; ++r) {
        float mx = fmaxf(fmaxf(sc_acc[fm][0][r], sc_acc[fm][1][r]),
                         fmaxf(sc_acc[fm][2][r], sc_acc[fm][3][r]));
#pragma unroll
        for (int d = 1; d < 16; d <<= 1) mx = fmaxf(mx, __shfl_xor(mx, d));
        const float mnew = fmaxf(m_run[fm][r], mx);
        const float fac = __expf(m_run[fm][r] - mnew);
        m_run[fm][r] = mnew;
        float rs = 0.f;
#pragma unroll
        for (int j = 0; j < 4; ++j) {
          const float p = __expf(sc_acc[fm][j][r] - mnew);
          sc_acc[fm][j][r] = p;
          rs += p;
        }
#pragma unroll
        for (int d = 1; d < 16; d <<= 1) rs += __shfl_xor(rs, d);
        l_run[fm][r] = l_run[fm][r] * fac + rs;
#pragma unroll
        for (int je = 0; je < 4; ++je) o[fm][je][r] *= fac;
      }
    }

    // P -> LDS (wave-private region; DS in-order per wave)
#pragma unroll
    for (int fm = 0; fm < 2; ++fm)
#pragma unroll
      for (int j = 0; j < 4; ++j)
#pragma unroll
        for (int r = 0; r < 4; ++r)
          sP[w * 32 + fm * 16 + (lane >> 4) * 4 + r][j * 16 + lr] = f2bf(sc_acc[fm][j][r]);
    asm volatile("s_waitcnt lgkmcnt(0)" ::: "memory");

    // PV: o += P(32x64) @ V(64x64)
    short8 pf[2][2], vf[4][2];
#pragma unroll
    for (int fm = 0; fm < 2; ++fm)
#pragma unroll
      for (int kk = 0; kk < 2; ++kk)
        pf[fm][kk] = *(const short8*)&sP[w * 32 + fm * 16 + lr][kk * 32 + lk];
#pragma unroll
    for (int je = 0; je < 4; ++je)
#pragma unroll
      for (int kk = 0; kk < 2; ++kk)
        vf[je][kk] = *(const short8*)&sV[je * 16 + lr][kk * 32 + lk];
#pragma unroll
    for (int fm = 0; fm < 2; ++fm)
#pragma unroll
      for (int je = 0; je < 4; ++je)
#pragma unroll
        for (int kk = 0; kk < 2; ++kk)
          o[fm][je] = __builtin_amdgcn_mfma_f32_16x16x32_bf16(pf[fm][kk], vf[je][kk], o[fm][je], 0, 0, 0);
  }

  // epilogue: normalize, stage in LDS, coalesced bf16 write
  float inv_l[2][4];
#pragma unroll
  for (int fm = 0; fm < 2; ++fm)
#pragma unroll
    for (int r = 0; r < 4; ++r) inv_l[fm][r] = 1.0f / l_run[fm][r];
#pragma unroll
  for (int fm = 0; fm < 2; ++fm)
#pragma unroll
    for (int je = 0; je < 4; ++je)
#pragma unroll
      for (int r = 0; r < 4; ++r)
        sP[w * 32 + fm * 16 + (lane >> 4) * 4 + r][je * 16 + lr] = f2bf(o[fm][je][r] * inv_l[fm][r]);
  __syncthreads();
  const int orow = tid >> 1, oc = (tid & 1) * 32;
  unsigned short* dst = &rep[(size_t)(b * 1024 + q0 + orow) * 768 + h * 64 + oc];
#pragma unroll
  for (int i = 0; i < 4; ++i)
    *(short8*)(dst + i * 8) = *(const short8*)&sP[orow][oc + i * 8];
}

// ---------------------------------------------------------------------------
// Output projection: out[8192,4096] = rep[8192,768] @ Wo^T + bo   (m97-style)
// 128x128 tile, BK=32, global_load_lds width 16, linear LDS.
// ---------------------------------------------------------------------------
__global__ __launch_bounds__(256) void oproj_kernel(const unsigned short* __restrict__ A,
                                                    const unsigned short* __restrict__ B,
                                                    const float* __restrict__ bo,
                                                    float* __restrict__ out) {
  __shared__ unsigned short sA[4096];
  __shared__ unsigned short sB[4096];
  const int tid = threadIdx.x;
  const int lane = tid & 63, wid = tid >> 6;
  const int wr = (wid >> 1) * 64, wc = (wid & 1) * 64;
  const int m0 = blockIdx.x * 128, n0 = blockIdx.y * 128;
  const int grow = lane >> 2;           // 0..15
  const int gcol = (lane & 3) * 8;      // 0,8,16,24
  const int lr = lane & 15, lk = (lane >> 4) * 8;

  f32x4 acc[4][4];
#pragma unroll
  for (int i = 0; i < 4; ++i)
#pragma unroll
    for (int j = 0; j < 4; ++j) acc[i][j] = (f32x4){0.f, 0.f, 0.f, 0.f};

  for (int k0 = 0; k0 < 768; k0 += 32) {
#pragma unroll
    for (int jj = 0; jj < 2; ++jj) {
      const int chunk = wid * 2 + jj;          // 0..7 -> 16 rows each
      const int row = chunk * 16 + grow;
      __builtin_amdgcn_global_load_lds(
          (const __attribute__((address_space(1))) unsigned int*)(A + (size_t)(m0 + row) * 768 + k0 + gcol),
          (__attribute__((address_space(3))) unsigned int*)(sA + chunk * 512),
          16, 0, 0);
      __builtin_amdgcn_global_load_lds(
          (const __attribute__((address_space(1))) unsigned int*)(B + (size_t)(n0 + row) * 768 + k0 + gcol),
          (__attribute__((address_space(3))) unsigned int*)(sB + chunk * 512),
          16, 0, 0);
    }
    __syncthreads();
    short8 af[4], bfr[4];
#pragma unroll
    for (int i = 0; i < 4; ++i) af[i]  = *(const short8*)&sA[(wr + i * 16 + lr) * 32 + lk];
#pragma unroll
    for (int j = 0; j < 4; ++j) bfr[j] = *(const short8*)&sB[(wc + j * 16 + lr) * 32 + lk];
#pragma unroll
    for (int i = 0; i < 4; ++i)
#pragma unroll
      for (int j = 0; j < 4; ++j)
        acc[i][j] = __builtin_amdgcn_mfma_f32_16x16x32_bf16(af[i], bfr[j], acc[i][j], 0, 0, 0);
    __syncthreads();
  }

#pragma unroll
  for (int i = 0; i < 4; ++i) {
#pragma unroll
    for (int j = 0; j < 4; ++j) {
      const int n = n0 + wc + j * 16 + lr;
      const float bv = bo[n];
      const int mb = m0 + wr + i * 16 + (lane >> 4) * 4;
#pragma unroll
      for (int r = 0; r < 4; ++r)
        out[(size_t)(mb + r) * 4096 + n] = acc[i][j][r] + bv;
    }
  }
}

// Wo fp32 -> bf16 (enables global_load_lds in oproj)
__global__ __launch_bounds__(256) void cvt_kernel(const float* __restrict__ in,
                                                  unsigned short* __restrict__ out) {
  const size_t i = ((size_t)blockIdx.x * 256 + threadIdx.x) * 8;  // < 3145728
  f32x4 a = *(const f32x4*)(in + i);
  f32x4 b = *(const f32x4*)(in + i + 4);
  short8 p;
#pragma unroll
  for (int j = 0; j < 4; ++j) p[j] = (short)f2bf(a[j]);
#pragma unroll
  for (int j = 0; j < 4; ++j) p[j + 4] = (short)f2bf(b[j]);
  *(short8*)&out[i] = p;
}

// ---------------------------------------------------------------------------
extern "C" void kernel_launch(void* const* d_in, const int* in_sizes, int n_in,
                              void* d_out, int out_size, void* d_ws, size_t ws_size,
                              hipStream_t stream) {
  const float* target = (const float*)d_in[0];
  const float* source = (const float*)d_in[1];
  const float* value  = (const float*)d_in[2];
  const float* Wq = (const float*)d_in[3];
  const float* bq = (const float*)d_in[4];
  const float* Wk = (const float*)d_in[5];
  const float* bk = (const float*)d_in[6];
  const float* Wv = (const float*)d_in[7];
  const float* bv = (const float*)d_in[8];
  const float* Wo = (const float*)d_in[9];
  const float* bo = (const float*)d_in[10];
  float* out = (float*)d_out;

  char* ws = (char*)d_ws;
  unsigned short* qb   = (unsigned short*)(ws);                 // [8192][768] bf16
  unsigned short* kb   = (unsigned short*)(ws + 12582912);      // [1024][768] bf16
  unsigned short* vtb  = (unsigned short*)(ws + 14155776);      // [768][1024] bf16 (V^T)
  unsigned short* repb = (unsigned short*)(ws + 15728640);      // [8192][768] bf16
  unsigned short* wob  = (unsigned short*)(ws + 28311552);      // [4096][768] bf16
  float* kacc = (float*)(ws + 34603008);                        // [1024][768] f32
  float* vacc = (float*)(ws + 37748736);                        // [1024][768] f32

  // zero split-K accumulators (contiguous)
  hipMemsetAsync(ws + 34603008, 0, 6291456, stream);

  cvt_kernel<<<1536, 256, 0, stream>>>(Wo, wob);
  qproj_kernel<<<dim3(64, 6), 256, 0, stream>>>(target, Wq, bq, qb);
  kvproj_kernel<<<dim3(8, 6, 8), 256, 0, stream>>>(source, value, Wk, Wv, kacc, vacc);
  finalize_kv<<<dim3(384, 1, 2), 256, 0, stream>>>(kacc, vacc, bk, bv, kb, vtb);
  attn_kernel<<<dim3(8, 96), 256, 0, stream>>>(qb, kb, vtb, repb);
  oproj_kernel<<<dim3(64, 32), 256, 0, stream>>>(repb, wob, bo, out);
}

// Round 2
// 521.059 us; speedup vs baseline: 1.0571x; 1.0571x over previous
//
#include <hip/hip_runtime.h>

typedef __attribute__((ext_vector_type(8))) short short8;
typedef __attribute__((ext_vector_type(4))) short short4v;
typedef __attribute__((ext_vector_type(4))) float f32x4;

#define DEVI __device__ __forceinline__

// fp32 -> bf16 round-to-nearest-even
DEVI unsigned short f2bf(float x) {
  unsigned u = __builtin_bit_cast(unsigned, x);
  u += 0x7fff + ((u >> 16) & 1u);
  return (unsigned short)(u >> 16);
}

// ---------------------------------------------------------------------------
// Projection GEMM: C[m,n] = sum_k A[m,k] * W[n,k]   (W is (out,in) = B^T form)
// Block tile = TM x TN, TM = 32*WM, TN = 32*WN. 256 threads = 4 waves (2x2),
// wave tile = (WM*16) x (WN*16). BK=32, reg-staged fp32->bf16 into padded LDS.
// MODE 0: out_bf16[m*ldo+n] = bf16((acc + bias[n]) * scale)
// MODE 2: atomicAdd(out_f32[m*ldo+n], acc)   (split-K partials, no bias)
// ---------------------------------------------------------------------------
template <int MODE, int WM, int WN>
DEVI void proj_body(const float* __restrict__ A, const float* __restrict__ W,
                    const float* __restrict__ bias, void* __restrict__ outp,
                    int M, int K, int ldo, float scale,
                    int bm, int bn, int kbeg, int kend) {
  constexpr int TM = WM * 32, TN = WN * 32, TR = TM + TN;
  __shared__ unsigned short sAB[TR][40];   // rows 0..TM-1 = A, TM.. = W
  const int tid  = threadIdx.x;
  const int lane = tid & 63, wid = tid >> 6;
  const int wr = (wid >> 1) * (WM * 16), wc = (wid & 1) * (WN * 16);
  const int m0 = bm * TM, n0 = bn * TN;
  const int srow = tid >> 3;            // 0..31 (+ p*32)
  const int scol = (tid & 7) * 4;       // 0..28
  const int lr = lane & 15, lk = (lane >> 4) * 8;

  f32x4 acc[WM][WN];
#pragma unroll
  for (int i = 0; i < WM; ++i)
#pragma unroll
    for (int j = 0; j < WN; ++j) acc[i][j] = (f32x4){0.f, 0.f, 0.f, 0.f};

  for (int k0 = kbeg; k0 < kend; k0 += 32) {
#pragma unroll
    for (int p = 0; p < TR / 32; ++p) {
      const int row = p * 32 + srow;
      f32x4 t;
      if (row < TM) {                      // A tile (guard rows >= M -> zeros)
        const int rg = m0 + row;
        t = (rg < M) ? *(const f32x4*)(A + (size_t)rg * K + k0 + scol)
                     : (f32x4){0.f, 0.f, 0.f, 0.f};
      } else {                             // W tile (N % TN == 0 always)
        t = *(const f32x4*)(W + (size_t)(n0 + row - TM) * K + k0 + scol);
      }
      short4v s;
#pragma unroll
      for (int j = 0; j < 4; ++j) s[j] = (short)f2bf(t[j]);
      *(short4v*)&sAB[row][scol] = s;
    }
    __syncthreads();
    short8 af[WM], bfr[WN];
#pragma unroll
    for (int i = 0; i < WM; ++i) af[i]  = *(const short8*)&sAB[wr + i * 16 + lr][lk];
#pragma unroll
    for (int j = 0; j < WN; ++j) bfr[j] = *(const short8*)&sAB[TM + wc + j * 16 + lr][lk];
#pragma unroll
    for (int i = 0; i < WM; ++i)
#pragma unroll
      for (int j = 0; j < WN; ++j)
        acc[i][j] = __builtin_amdgcn_mfma_f32_16x16x32_bf16(af[i], bfr[j], acc[i][j], 0, 0, 0);
    __syncthreads();
  }

  // C-write. C/D layout: col = lane&15, row = (lane>>4)*4 + r  [m89-verified]
#pragma unroll
  for (int i = 0; i < WM; ++i) {
#pragma unroll
    for (int j = 0; j < WN; ++j) {
      const int n  = n0 + wc + j * 16 + lr;
      const int mb = m0 + wr + i * 16 + (lane >> 4) * 4;
      if (MODE == 0) {
        const float bv = bias[n];
        unsigned short* out = (unsigned short*)outp;
#pragma unroll
        for (int r = 0; r < 4; ++r)
          out[(size_t)(mb + r) * ldo + n] = f2bf((acc[i][j][r] + bv) * scale);
      } else {
        float* out = (float*)outp;   // partial buffers padded to TM multiple
#pragma unroll
        for (int r = 0; r < 4; ++r)
          atomicAdd(&out[(size_t)(mb + r) * ldo + n], acc[i][j][r]);
      }
    }
  }
}

// Q projection: (8192x768) @ Wq^T + bq, scaled by 1/8 (folded attention scale)
// 64x128 tiles -> grid (128, 6) = 768 blocks
__global__ __launch_bounds__(256) void qproj_kernel(const float* __restrict__ target,
                                                    const float* __restrict__ Wq,
                                                    const float* __restrict__ bq,
                                                    unsigned short* __restrict__ qb) {
  proj_body<0, 2, 4>(target, Wq, bq, qb, 8192, 768, 768, 0.125f,
                     blockIdx.x, blockIdx.y, 0, 768);
}

// K/V projections, split-K x8: z = kv*8 + ksplit. fp32 atomic partials.
// 64x128 tiles -> grid (16, 6, 16) = 1536 blocks
__global__ __launch_bounds__(256) void kvproj_kernel(const float* __restrict__ source,
                                                     const float* __restrict__ value,
                                                     const float* __restrict__ Wk,
                                                     const float* __restrict__ Wv,
                                                     float* __restrict__ kacc,
                                                     float* __restrict__ vacc) {
  const int kv = blockIdx.z >> 3, ks = blockIdx.z & 7;
  const float* A = kv ? value : source;
  const float* W = kv ? Wv : Wk;
  float* out = kv ? vacc : kacc;
  proj_body<2, 2, 4>(A, W, nullptr, out, 1000, 4096, 768, 1.0f,
                     blockIdx.x, blockIdx.y, ks * 512, ks * 512 + 512);
}

// finalize: z=0  kb[s][n]   = bf16(kacc + bk)          (1024x768)
//           z=1  vtb[n][s]  = bf16(vacc^T + bv)        (768x1024, transposed)
__global__ __launch_bounds__(256) void finalize_kv(const float* __restrict__ kacc,
                                                   const float* __restrict__ vacc,
                                                   const float* __restrict__ bk,
                                                   const float* __restrict__ bv,
                                                   unsigned short* __restrict__ kb,
                                                   unsigned short* __restrict__ vtb) {
  if (blockIdx.z == 0) {
    const int i = (blockIdx.x * 256 + threadIdx.x) * 8;  // < 786432
    const int col = i % 768;
    short8 p;
#pragma unroll
    for (int j = 0; j < 8; ++j) p[j] = (short)f2bf(kacc[i + j] + bk[col + j]);
    *(short8*)&kb[i] = p;
  } else {
    const int idx = blockIdx.x * 256 + threadIdx.x;      // < 98304
    const int n = idx >> 7;
    const int s0 = (idx & 127) * 8;
    const float bvn = bv[n];
    short8 p;
#pragma unroll
    for (int j = 0; j < 8; ++j) p[j] = (short)f2bf(vacc[(size_t)(s0 + j) * 768 + n] + bvn);
    *(short8*)&vtb[(size_t)n * 1024 + s0] = p;
  }
}

// ---------------------------------------------------------------------------
// Flash cross-attention. Grid (L/128, B*H). 4 waves; wave w owns 32 q-rows.
// KV-tile = 64. sK[s][e], sV[e][s] (V pre-transposed), sP per-wave P buffer.
// Online softmax in MFMA C-layout; 16-lane shfl_xor row reduction.
// ---------------------------------------------------------------------------
__global__ __launch_bounds__(256) void attn_kernel(const unsigned short* __restrict__ q,
                                                   const unsigned short* __restrict__ k,
                                                   const unsigned short* __restrict__ vt,
                                                   unsigned short* __restrict__ rep) {
  __shared__ unsigned short sK[64][72];
  __shared__ unsigned short sV[64][72];
  __shared__ unsigned short sP[128][72];

  const int tid = threadIdx.x;
  const int lane = tid & 63, w = tid >> 6;
  const int q0 = blockIdx.x * 128;
  const int b = blockIdx.y / 12, h = blockIdx.y % 12;
  const int lr = lane & 15, lk = (lane >> 4) * 8;
  const int qrow_base = b * 1024 + q0 + w * 32;

  // Q fragments live in registers for the whole block
  short8 qf[2][2];
#pragma unroll
  for (int fm = 0; fm < 2; ++fm)
#pragma unroll
    for (int kk = 0; kk < 2; ++kk)
      qf[fm][kk] = *(const short8*)&q[(size_t)(qrow_base + fm * 16 + lr) * 768 + h * 64 + kk * 32 + lk];

  float m_run[2][4], l_run[2][4];
  f32x4 o[2][4];
#pragma unroll
  for (int fm = 0; fm < 2; ++fm)
#pragma unroll
    for (int r = 0; r < 4; ++r) {
      m_run[fm][r] = -1e30f;
      l_run[fm][r] = 0.f;
    }
#pragma unroll
  for (int fm = 0; fm < 2; ++fm)
#pragma unroll
    for (int je = 0; je < 4; ++je) o[fm][je] = (f32x4){0.f, 0.f, 0.f, 0.f};

  const int strow = tid >> 2;           // 0..63
  const int stc = (tid & 3) * 16;       // 0,16,32,48

  for (int t = 0; t < 16; ++t) {
    const int s0 = t * 64;
    __syncthreads();
    {  // stage K tile [s][e] and V^T tile [e][s]
      const unsigned short* ks = &k[(size_t)(s0 + strow) * 768 + h * 64 + stc];
      *(short8*)&sK[strow][stc]     = *(const short8*)ks;
      *(short8*)&sK[strow][stc + 8] = *(const short8*)(ks + 8);
      const unsigned short* vs = &vt[(size_t)(h * 64 + strow) * 1024 + s0 + stc];
      *(short8*)&sV[strow][stc]     = *(const short8*)vs;
      *(short8*)&sV[strow][stc + 8] = *(const short8*)(vs + 8);
    }
    __syncthreads();

    // QK^T: scores 32(q) x 64(s) per wave
    f32x4 sc_acc[2][4];
#pragma unroll
    for (int fm = 0; fm < 2; ++fm)
#pragma unroll
      for (int j = 0; j < 4; ++j) sc_acc[fm][j] = (f32x4){0.f, 0.f, 0.f, 0.f};
    short8 kf[4][2];
#pragma unroll
    for (int j = 0; j < 4; ++j)
#pragma unroll
      for (int kk = 0; kk < 2; ++kk)
        kf[j][kk] = *(const short8*)&sK[j * 16 + lr][kk * 32 + lk];
#pragma unroll
    for (int fm = 0; fm < 2; ++fm)
#pragma unroll
      for (int j = 0; j < 4; ++j)
#pragma unroll
        for (int kk = 0; kk < 2; ++kk)
          sc_acc[fm][j] = __builtin_amdgcn_mfma_f32_16x16x32_bf16(qf[fm][kk], kf[j][kk], sc_acc[fm][j], 0, 0, 0);

    // tail mask (s >= 1000) — only last tile
    if (s0 + 64 > 1000) {
#pragma unroll
      for (int j = 0; j < 4; ++j)
        if (s0 + j * 16 + lr >= 1000) {
#pragma unroll
          for (int fm = 0; fm < 2; ++fm)
#pragma unroll
            for (int r = 0; r < 4; ++r) sc_acc[fm][j][r] = -1e30f;
        }
    }

    // online softmax (rows live in (lane>>4, r); 16-lane groups share a row)
#pragma unroll
    for (int fm = 0; fm < 2; ++fm) {
#pragma unroll
      for (int r = 0; r < 4; ++r) {
        float mx = fmaxf(fmaxf(sc_acc[fm][0][r], sc_acc[fm][1][r]),
                         fmaxf(sc_acc[fm][2][r], sc_acc[fm][3][r]));
#pragma unroll
        for (int d = 1; d < 16; d <<= 1) mx = fmaxf(mx, __shfl_xor(mx, d));
        const float mnew = fmaxf(m_run[fm][r], mx);
        const float fac = __expf(m_run[fm][r] - mnew);
        m_run[fm][r] = mnew;
        float rs = 0.f;
#pragma unroll
        for (int j = 0; j < 4; ++j) {
          const float p = __expf(sc_acc[fm][j][r] - mnew);
          sc_acc[fm][j][r] = p;
          rs += p;
        }
#pragma unroll
        for (int d = 1; d < 16; d <<= 1) rs += __shfl_xor(rs, d);
        l_run[fm][r] = l_run[fm][r] * fac + rs;
#pragma unroll
        for (int je = 0; je < 4; ++je) o[fm][je][r] *= fac;
      }
    }

    // P -> LDS (wave-private region; DS in-order per wave)
#pragma unroll
    for (int fm = 0; fm < 2; ++fm)
#pragma unroll
      for (int j = 0; j < 4; ++j)
#pragma unroll
        for (int r = 0; r < 4; ++r)
          sP[w * 32 + fm * 16 + (lane >> 4) * 4 + r][j * 16 + lr] = f2bf(sc_acc[fm][j][r]);
    asm volatile("s_waitcnt lgkmcnt(0)" ::: "memory");

    // PV: o += P(32x64) @ V(64x64)
    short8 pf[2][2], vf[4][2];
#pragma unroll
    for (int fm = 0; fm < 2; ++fm)
#pragma unroll
      for (int kk = 0; kk < 2; ++kk)
        pf[fm][kk] = *(const short8*)&sP[w * 32 + fm * 16 + lr][kk * 32 + lk];
#pragma unroll
    for (int je = 0; je < 4; ++je)
#pragma unroll
      for (int kk = 0; kk < 2; ++kk)
        vf[je][kk] = *(const short8*)&sV[je * 16 + lr][kk * 32 + lk];
#pragma unroll
    for (int fm = 0; fm < 2; ++fm)
#pragma unroll
      for (int je = 0; je < 4; ++je)
#pragma unroll
        for (int kk = 0; kk < 2; ++kk)
          o[fm][je] = __builtin_amdgcn_mfma_f32_16x16x32_bf16(pf[fm][kk], vf[je][kk], o[fm][je], 0, 0, 0);
  }

  // epilogue: normalize, stage in LDS, coalesced bf16 write
  float inv_l[2][4];
#pragma unroll
  for (int fm = 0; fm < 2; ++fm)
#pragma unroll
    for (int r = 0; r < 4; ++r) inv_l[fm][r] = 1.0f / l_run[fm][r];
#pragma unroll
  for (int fm = 0; fm < 2; ++fm)
#pragma unroll
    for (int je = 0; je < 4; ++je)
#pragma unroll
      for (int r = 0; r < 4; ++r)
        sP[w * 32 + fm * 16 + (lane >> 4) * 4 + r][je * 16 + lr] = f2bf(o[fm][je][r] * inv_l[fm][r]);
  __syncthreads();
  const int orow = tid >> 1, oc = (tid & 1) * 32;
  unsigned short* dst = &rep[(size_t)(b * 1024 + q0 + orow) * 768 + h * 64 + oc];
#pragma unroll
  for (int i = 0; i < 4; ++i)
    *(short8*)(dst + i * 8) = *(const short8*)&sP[orow][oc + i * 8];
}

// ---------------------------------------------------------------------------
// Output projection: out[8192,4096] = rep[8192,768] @ Wo^T + bo   (m97-style)
// 128x128 tile, BK=32, global_load_lds width 16, linear LDS.
// ---------------------------------------------------------------------------
__global__ __launch_bounds__(256) void oproj_kernel(const unsigned short* __restrict__ A,
                                                    const unsigned short* __restrict__ B,
                                                    const float* __restrict__ bo,
                                                    float* __restrict__ out) {
  __shared__ unsigned short sA[4096];
  __shared__ unsigned short sB[4096];
  const int tid = threadIdx.x;
  const int lane = tid & 63, wid = tid >> 6;
  const int wr = (wid >> 1) * 64, wc = (wid & 1) * 64;
  const int m0 = blockIdx.x * 128, n0 = blockIdx.y * 128;
  const int grow = lane >> 2;           // 0..15
  const int gcol = (lane & 3) * 8;      // 0,8,16,24
  const int lr = lane & 15, lk = (lane >> 4) * 8;

  f32x4 acc[4][4];
#pragma unroll
  for (int i = 0; i < 4; ++i)
#pragma unroll
    for (int j = 0; j < 4; ++j) acc[i][j] = (f32x4){0.f, 0.f, 0.f, 0.f};

  for (int k0 = 0; k0 < 768; k0 += 32) {
#pragma unroll
    for (int jj = 0; jj < 2; ++jj) {
      const int chunk = wid * 2 + jj;          // 0..7 -> 16 rows each
      const int row = chunk * 16 + grow;
      __builtin_amdgcn_global_load_lds(
          (const __attribute__((address_space(1))) unsigned int*)(A + (size_t)(m0 + row) * 768 + k0 + gcol),
          (__attribute__((address_space(3))) unsigned int*)(sA + chunk * 512),
          16, 0, 0);
      __builtin_amdgcn_global_load_lds(
          (const __attribute__((address_space(1))) unsigned int*)(B + (size_t)(n0 + row) * 768 + k0 + gcol),
          (__attribute__((address_space(3))) unsigned int*)(sB + chunk * 512),
          16, 0, 0);
    }
    __syncthreads();
    short8 af[4], bfr[4];
#pragma unroll
    for (int i = 0; i < 4; ++i) af[i]  = *(const short8*)&sA[(wr + i * 16 + lr) * 32 + lk];
#pragma unroll
    for (int j = 0; j < 4; ++j) bfr[j] = *(const short8*)&sB[(wc + j * 16 + lr) * 32 + lk];
#pragma unroll
    for (int i = 0; i < 4; ++i)
#pragma unroll
      for (int j = 0; j < 4; ++j)
        acc[i][j] = __builtin_amdgcn_mfma_f32_16x16x32_bf16(af[i], bfr[j], acc[i][j], 0, 0, 0);
    __syncthreads();
  }

#pragma unroll
  for (int i = 0; i < 4; ++i) {
#pragma unroll
    for (int j = 0; j < 4; ++j) {
      const int n = n0 + wc + j * 16 + lr;
      const float bv = bo[n];
      const int mb = m0 + wr + i * 16 + (lane >> 4) * 4;
#pragma unroll
      for (int r = 0; r < 4; ++r)
        out[(size_t)(mb + r) * 4096 + n] = acc[i][j][r] + bv;
    }
  }
}

// Wo fp32 -> bf16 (enables global_load_lds in oproj)
__global__ __launch_bounds__(256) void cvt_kernel(const float* __restrict__ in,
                                                  unsigned short* __restrict__ out) {
  const size_t i = ((size_t)blockIdx.x * 256 + threadIdx.x) * 8;  // < 3145728
  f32x4 a = *(const f32x4*)(in + i);
  f32x4 b = *(const f32x4*)(in + i + 4);
  short8 p;
#pragma unroll
  for (int j = 0; j < 4; ++j) p[j] = (short)f2bf(a[j]);
#pragma unroll
  for (int j = 0; j < 4; ++j) p[j + 4] = (short)f2bf(b[j]);
  *(short8*)&out[i] = p;
}

// ---------------------------------------------------------------------------
extern "C" void kernel_launch(void* const* d_in, const int* in_sizes, int n_in,
                              void* d_out, int out_size, void* d_ws, size_t ws_size,
                              hipStream_t stream) {
  const float* target = (const float*)d_in[0];
  const float* source = (const float*)d_in[1];
  const float* value  = (const float*)d_in[2];
  const float* Wq = (const float*)d_in[3];
  const float* bq = (const float*)d_in[4];
  const float* Wk = (const float*)d_in[5];
  const float* bk = (const float*)d_in[6];
  const float* Wv = (const float*)d_in[7];
  const float* bv = (const float*)d_in[8];
  const float* Wo = (const float*)d_in[9];
  const float* bo = (const float*)d_in[10];
  float* out = (float*)d_out;

  char* ws = (char*)d_ws;
  unsigned short* qb   = (unsigned short*)(ws);                 // [8192][768] bf16
  unsigned short* kb   = (unsigned short*)(ws + 12582912);      // [1024][768] bf16
  unsigned short* vtb  = (unsigned short*)(ws + 14155776);      // [768][1024] bf16 (V^T)
  unsigned short* repb = (unsigned short*)(ws + 15728640);      // [8192][768] bf16
  unsigned short* wob  = (unsigned short*)(ws + 28311552);      // [4096][768] bf16
  float* kacc = (float*)(ws + 34603008);                        // [1024][768] f32
  float* vacc = (float*)(ws + 37748736);                        // [1024][768] f32

  // zero split-K accumulators (contiguous)
  hipMemsetAsync(ws + 34603008, 0, 6291456, stream);

  cvt_kernel<<<1536, 256, 0, stream>>>(Wo, wob);
  qproj_kernel<<<dim3(128, 6), 256, 0, stream>>>(target, Wq, bq, qb);
  kvproj_kernel<<<dim3(16, 6, 16), 256, 0, stream>>>(source, value, Wk, Wv, kacc, vacc);
  finalize_kv<<<dim3(384, 1, 2), 256, 0, stream>>>(kacc, vacc, bk, bv, kb, vtb);
  attn_kernel<<<dim3(8, 96), 256, 0, stream>>>(qb, kb, vtb, repb);
  oproj_kernel<<<dim3(64, 32), 256, 0, stream>>>(repb, wob, bo, out);
}

// Round 4
// 448.232 us; speedup vs baseline: 1.2289x; 1.1625x over previous
//
#include <hip/hip_runtime.h>

typedef __attribute__((ext_vector_type(8))) short short8;
typedef __attribute__((ext_vector_type(4))) float f32x4;
typedef __attribute__((ext_vector_type(2))) unsigned u32x2;

#define DEVI __device__ __forceinline__

// fp32 -> bf16 round-to-nearest-even
DEVI unsigned short f2bf(float x) {
  unsigned u = __builtin_bit_cast(unsigned, x);
  u += 0x7fff + ((u >> 16) & 1u);
  return (unsigned short)(u >> 16);
}

// pack two fp32 -> bf16x2 word (lo = a, hi = b)
DEVI unsigned pkbf2(float a, float b) {
  return (unsigned)f2bf(a) | ((unsigned)f2bf(b) << 16);
}

// ---------------------------------------------------------------------------
// One-pass fp32 -> bf16 conversion of all GEMM inputs (7 tensors).
// vec8 unit counts (compile-time): target 786432 | source 512000 | value
// 512000 | Wq 73728 | Wk 393216 | Wv 393216 | Wo 393216; total 3063808.
// ---------------------------------------------------------------------------
__global__ __launch_bounds__(256) void cvt_all(
    const float* __restrict__ t0, const float* __restrict__ t1,
    const float* __restrict__ t2, const float* __restrict__ t3,
    const float* __restrict__ t4, const float* __restrict__ t5,
    const float* __restrict__ t6,
    unsigned short* __restrict__ o0, unsigned short* __restrict__ o1,
    unsigned short* __restrict__ o2, unsigned short* __restrict__ o3,
    unsigned short* __restrict__ o4, unsigned short* __restrict__ o5,
    unsigned short* __restrict__ o6) {
  const unsigned gid = blockIdx.x * 256 + threadIdx.x;
  const float* src;
  unsigned short* dst;
  unsigned base;
  if (gid < 786432u)       { src = t0; dst = o0; base = 0u; }
  else if (gid < 1298432u) { src = t1; dst = o1; base = 786432u; }
  else if (gid < 1810432u) { src = t2; dst = o2; base = 1298432u; }
  else if (gid < 1884160u) { src = t3; dst = o3; base = 1810432u; }
  else if (gid < 2277376u) { src = t4; dst = o4; base = 1884160u; }
  else if (gid < 2670592u) { src = t5; dst = o5; base = 2277376u; }
  else                     { src = t6; dst = o6; base = 2670592u; }
  const size_t i = (size_t)(gid - base) * 8;
  f32x4 a = *(const f32x4*)(src + i);
  f32x4 b = *(const f32x4*)(src + i + 4);
  short8 p;
#pragma unroll
  for (int j = 0; j < 4; ++j) p[j] = (short)f2bf(a[j]);
#pragma unroll
  for (int j = 0; j < 4; ++j) p[j + 4] = (short)f2bf(b[j]);
  *(short8*)&dst[i] = p;
}

// ---------------------------------------------------------------------------
// m97-style bf16 GEMM: C[m,n] = sum_k A[m,k] * B[n,k], global_load_lds w=16.
// Tile TM x 128, BK=32, 256 threads = 4 waves (2x2), wave tile (TM/2) x 64.
// A rows clamped to M-1 (junk rows masked downstream).
// MODE 0: bf16 out, (acc+bias)*scale | MODE 1: f32 out, acc+bias
// MODE 2: f32 out, raw acc (split-K partial)
// ---------------------------------------------------------------------------
template <int TM, int MODE>
DEVI void gemm_body(const unsigned short* __restrict__ A,
                    const unsigned short* __restrict__ B,
                    const float* __restrict__ bias, void* __restrict__ outp,
                    int M, int lda, int ldo, float scale,
                    int bm, int bn, int kbeg, int kend) {
  constexpr int WM = TM / 32;          // A-frags per wave
  constexpr int ROWS = TM + 128;       // A rows then B rows in one LDS buffer
  constexpr int NCH = ROWS / 16;       // 16-row chunks (1 KiB = 1 wave-load)
  constexpr int CPW = NCH / 4;
  __shared__ unsigned short sAB[ROWS * 32];
  const int tid = threadIdx.x;
  const int lane = tid & 63, wid = tid >> 6;
  const int wr = (wid >> 1) * (WM * 16), wc = (wid & 1) * 64;
  const int m0 = bm * TM, n0 = bn * 128;
  const int grow = lane >> 2, gcol = (lane & 3) * 8;
  const int lr = lane & 15, lk = (lane >> 4) * 8;

  f32x4 acc[WM][4];
#pragma unroll
  for (int i = 0; i < WM; ++i)
#pragma unroll
    for (int j = 0; j < 4; ++j) acc[i][j] = (f32x4){0.f, 0.f, 0.f, 0.f};

  for (int k0 = kbeg; k0 < kend; k0 += 32) {
#pragma unroll
    for (int i = 0; i < CPW; ++i) {
      const int c = wid * CPW + i;          // wave-uniform chunk id
      const int row = c * 16 + grow;
      const unsigned short* src;
      if (c * 16 < TM) {                    // uniform: chunk fully in A
        int rg = m0 + row;
        if (rg > M - 1) rg = M - 1;         // clamp (finite junk, masked later)
        src = A + (size_t)rg * lda + k0 + gcol;
      } else {
        src = B + (size_t)(n0 + row - TM) * lda + k0 + gcol;
      }
      __builtin_amdgcn_global_load_lds(
          (const __attribute__((address_space(1))) unsigned int*)src,
          (__attribute__((address_space(3))) unsigned int*)(sAB + c * 512),
          16, 0, 0);
    }
    __syncthreads();
    short8 af[WM], bfr[4];
#pragma unroll
    for (int i = 0; i < WM; ++i) af[i]  = *(const short8*)&sAB[(wr + i * 16 + lr) * 32 + lk];
#pragma unroll
    for (int j = 0; j < 4; ++j)  bfr[j] = *(const short8*)&sAB[(TM + wc + j * 16 + lr) * 32 + lk];
#pragma unroll
    for (int i = 0; i < WM; ++i)
#pragma unroll
      for (int j = 0; j < 4; ++j)
        acc[i][j] = __builtin_amdgcn_mfma_f32_16x16x32_bf16(af[i], bfr[j], acc[i][j], 0, 0, 0);
    __syncthreads();
  }

  // C-write. C/D layout: col = lane&15, row = (lane>>4)*4 + r
#pragma unroll
  for (int i = 0; i < WM; ++i) {
#pragma unroll
    for (int j = 0; j < 4; ++j) {
      const int n  = n0 + wc + j * 16 + lr;
      const int mb = m0 + wr + i * 16 + (lane >> 4) * 4;
      if (MODE == 0) {
        const float bv = bias[n];
        unsigned short* out = (unsigned short*)outp;
#pragma unroll
        for (int r = 0; r < 4; ++r)
          out[(size_t)(mb + r) * ldo + n] = f2bf((acc[i][j][r] + bv) * scale);
      } else if (MODE == 1) {
        const float bv = bias[n];
        float* out = (float*)outp;
#pragma unroll
        for (int r = 0; r < 4; ++r)
          out[(size_t)(mb + r) * ldo + n] = acc[i][j][r] + bv;
      } else {
        float* out = (float*)outp;          // partial buffer padded to 1024 rows
#pragma unroll
        for (int r = 0; r < 4; ++r)
          out[(size_t)(mb + r) * ldo + n] = acc[i][j][r];
      }
    }
  }
}

// Q projection: (8192x768)@Wq^T + bq, scale = 1/8 * log2(e)  (exp2 softmax)
__global__ __launch_bounds__(256) void qproj_kernel(const unsigned short* __restrict__ A,
                                                    const unsigned short* __restrict__ B,
                                                    const float* __restrict__ bq,
                                                    unsigned short* __restrict__ qb) {
  gemm_body<64, 0>(A, B, bq, qb, 8192, 768, 768, 0.18033688011112042f,
                   blockIdx.x, blockIdx.y, 0, 768);
}

// K/V projections, split-K x4 into separate partial buffers (no atomics).
// z = mat*4 + ks. Grid (16, 6, 8).
__global__ __launch_bounds__(256) void kvproj_kernel(const unsigned short* __restrict__ sb,
                                                     const unsigned short* __restrict__ vb,
                                                     const unsigned short* __restrict__ wkb,
                                                     const unsigned short* __restrict__ wvb,
                                                     float* __restrict__ parts) {
  const int mat = blockIdx.z >> 2, ks = blockIdx.z & 3;
  const unsigned short* A = mat ? vb : sb;
  const unsigned short* B = mat ? wvb : wkb;
  float* out = parts + (size_t)blockIdx.z * 786432;   // [1024][768] f32 each
  gemm_body<64, 2>(A, B, nullptr, out, 1000, 4096, 768, 1.0f,
                   blockIdx.x, blockIdx.y, ks * 1024, ks * 1024 + 1024);
}

// Output projection: out[8192,4096] = rep@Wo^T + bo
__global__ __launch_bounds__(256) void oproj_kernel(const unsigned short* __restrict__ A,
                                                    const unsigned short* __restrict__ B,
                                                    const float* __restrict__ bo,
                                                    float* __restrict__ out) {
  gemm_body<128, 1>(A, B, bo, out, 8192, 768, 4096, 1.0f,
                    blockIdx.x, blockIdx.y, 0, 768);
}

// finalize: z=0  kb[s][n]  = bf16(sum_ks kpart + bk)     (1024x768)
//           z=1  vtb[n][s] = bf16(sum_ks vpart^T + bv)   (768x1024, transposed)
__global__ __launch_bounds__(256) void finalize_kv(const float* __restrict__ parts,
                                                   const float* __restrict__ bk,
                                                   const float* __restrict__ bv,
                                                   unsigned short* __restrict__ kb,
                                                   unsigned short* __restrict__ vtb) {
  if (blockIdx.z == 0) {
    const int i = (blockIdx.x * 256 + threadIdx.x) * 8;  // < 786432
    const int col = i % 768;
    f32x4 sa = (f32x4){0.f, 0.f, 0.f, 0.f}, sb = sa;
#pragma unroll
    for (int p = 0; p < 4; ++p) {
      sa += *(const f32x4*)(parts + (size_t)p * 786432 + i);
      sb += *(const f32x4*)(parts + (size_t)p * 786432 + i + 4);
    }
    short8 o;
#pragma unroll
    for (int j = 0; j < 4; ++j) o[j] = (short)f2bf(sa[j] + bk[col + j]);
#pragma unroll
    for (int j = 0; j < 4; ++j) o[j + 4] = (short)f2bf(sb[j] + bk[col + 4 + j]);
    *(short8*)&kb[i] = o;
  } else {
    const int idx = blockIdx.x * 256 + threadIdx.x;      // < 98304
    const int n = idx >> 7;
    const int s0 = (idx & 127) * 8;
    const float bvn = bv[n];
    short8 o;
#pragma unroll
    for (int j = 0; j < 8; ++j) {
      float s = 0.f;
#pragma unroll
      for (int p = 0; p < 4; ++p)
        s += parts[(size_t)(4 + p) * 786432 + (size_t)(s0 + j) * 768 + n];
      o[j] = (short)f2bf(s + bvn);
    }
    *(short8*)&vtb[(size_t)n * 1024 + s0] = o;
  }
}

// ---------------------------------------------------------------------------
// Flash cross-attention, SWAPPED QK^T: sc = mfma(K, Q) -> D[s][q], so each
// lane owns q-row (lane&15); row-reduce = in-lane tree + 2 shfl_xor.
// P packed via pkbf2 -> 8x ds_write_b64 (2-way, conflict-free); P col == s,
// so PV A-fragment reads are the plain layout. exp2 domain (log2e folded
// into q scale). Grid (L/128, B*H), 4 waves x 32 q-rows.
// ---------------------------------------------------------------------------
__global__ __launch_bounds__(256) void attn_kernel(const unsigned short* __restrict__ q,
                                                   const unsigned short* __restrict__ k,
                                                   const unsigned short* __restrict__ vt,
                                                   unsigned short* __restrict__ rep) {
  __shared__ unsigned short sK[64][72];
  __shared__ unsigned short sV[64][72];
  __shared__ unsigned short sP[128][72];

  const int tid = threadIdx.x;
  const int lane = tid & 63, w = tid >> 6;
  const int g = lane >> 4;
  const int q0 = blockIdx.x * 128;
  const int b = blockIdx.y / 12, h = blockIdx.y % 12;
  const int lr = lane & 15, lk = g * 8;
  const int qrow_base = b * 1024 + q0 + w * 32;

  short8 qf[2][2];
#pragma unroll
  for (int fm = 0; fm < 2; ++fm)
#pragma unroll
    for (int kk = 0; kk < 2; ++kk)
      qf[fm][kk] = *(const short8*)&q[(size_t)(qrow_base + fm * 16 + lr) * 768 + h * 64 + kk * 32 + lk];

  float m_run[2] = {-1e30f, -1e30f};
  float l_run[2] = {0.f, 0.f};
  f32x4 o[2][4];
#pragma unroll
  for (int fm = 0; fm < 2; ++fm)
#pragma unroll
    for (int je = 0; je < 4; ++je) o[fm][je] = (f32x4){0.f, 0.f, 0.f, 0.f};

  const int strow = tid >> 2, stc = (tid & 3) * 16;

  for (int t = 0; t < 16; ++t) {
    const int s0 = t * 64;
    __syncthreads();
    {  // stage K tile [s][e] and V^T tile [e][s]
      const unsigned short* ks = &k[(size_t)(s0 + strow) * 768 + h * 64 + stc];
      *(short8*)&sK[strow][stc]     = *(const short8*)ks;
      *(short8*)&sK[strow][stc + 8] = *(const short8*)(ks + 8);
      const unsigned short* vs = &vt[(size_t)(h * 64 + strow) * 1024 + s0 + stc];
      *(short8*)&sV[strow][stc]     = *(const short8*)vs;
      *(short8*)&sV[strow][stc + 8] = *(const short8*)(vs + 8);
    }
    __syncthreads();

    // QK^T swapped: sc[fm][j] = D[s=j*16+g*4+r][q=fm*16+lr]
    f32x4 sc[2][4];
#pragma unroll
    for (int fm = 0; fm < 2; ++fm)
#pragma unroll
      for (int j = 0; j < 4; ++j) sc[fm][j] = (f32x4){0.f, 0.f, 0.f, 0.f};
    short8 kf[4][2];
#pragma unroll
    for (int j = 0; j < 4; ++j)
#pragma unroll
      for (int kk = 0; kk < 2; ++kk)
        kf[j][kk] = *(const short8*)&sK[j * 16 + lr][kk * 32 + lk];
#pragma unroll
    for (int fm = 0; fm < 2; ++fm)
#pragma unroll
      for (int j = 0; j < 4; ++j)
#pragma unroll
        for (int kk = 0; kk < 2; ++kk)
          sc[fm][j] = __builtin_amdgcn_mfma_f32_16x16x32_bf16(kf[j][kk], qf[fm][kk], sc[fm][j], 0, 0, 0);

    // tail mask: s index = s0 + j*16 + g*4 + r
    if (s0 + 64 > 1000) {
#pragma unroll
      for (int j = 0; j < 4; ++j)
#pragma unroll
        for (int r = 0; r < 4; ++r)
          if (s0 + j * 16 + g * 4 + r >= 1000) {
            sc[0][j][r] = -1e30f;
            sc[1][j][r] = -1e30f;
          }
    }

    // online softmax in log2 domain; per-lane q-row per fm
    float fac[2];
#pragma unroll
    for (int fm = 0; fm < 2; ++fm) {
      float mx = -1e30f;
#pragma unroll
      for (int j = 0; j < 4; ++j) {
        float a = fmaxf(fmaxf(sc[fm][j][0], sc[fm][j][1]),
                        fmaxf(sc[fm][j][2], sc[fm][j][3]));
        mx = fmaxf(mx, a);
      }
      mx = fmaxf(mx, __shfl_xor(mx, 16));
      mx = fmaxf(mx, __shfl_xor(mx, 32));
      const float mnew = fmaxf(m_run[fm], mx);
      fac[fm] = exp2f(m_run[fm] - mnew);
      m_run[fm] = mnew;
      float rs = 0.f;
#pragma unroll
      for (int j = 0; j < 4; ++j)
#pragma unroll
        for (int r = 0; r < 4; ++r) {
          const float p = exp2f(sc[fm][j][r] - mnew);
          sc[fm][j][r] = p;
          rs += p;
        }
      rs += __shfl_xor(rs, 16);
      rs += __shfl_xor(rs, 32);
      l_run[fm] = l_run[fm] * fac[fm] + rs;
    }

    // rescale o (rows q = fm*16 + g*4 + r): broadcast fac from lane 20g+r
#pragma unroll
    for (int fm = 0; fm < 2; ++fm)
#pragma unroll
      for (int r = 0; r < 4; ++r) {
        const float fq = __shfl(fac[fm], g * 20 + r);
#pragma unroll
        for (int je = 0; je < 4; ++je) o[fm][je][r] *= fq;
      }

    // P -> LDS: packed quads, col == s (wave-private rows; DS in-order)
#pragma unroll
    for (int fm = 0; fm < 2; ++fm)
#pragma unroll
      for (int j = 0; j < 4; ++j) {
        u32x2 pw;
        pw[0] = pkbf2(sc[fm][j][0], sc[fm][j][1]);
        pw[1] = pkbf2(sc[fm][j][2], sc[fm][j][3]);
        *(u32x2*)&sP[w * 32 + fm * 16 + lr][j * 16 + g * 4] = pw;
      }
    asm volatile("s_waitcnt lgkmcnt(0)" ::: "memory");

    // PV: o += P(32x64) @ V(64x64)
    short8 pf[2][2], vf[4][2];
#pragma unroll
    for (int fm = 0; fm < 2; ++fm)
#pragma unroll
      for (int kk = 0; kk < 2; ++kk)
        pf[fm][kk] = *(const short8*)&sP[w * 32 + fm * 16 + lr][kk * 32 + lk];
#pragma unroll
    for (int je = 0; je < 4; ++je)
#pragma unroll
      for (int kk = 0; kk < 2; ++kk)
        vf[je][kk] = *(const short8*)&sV[je * 16 + lr][kk * 32 + lk];
#pragma unroll
    for (int fm = 0; fm < 2; ++fm)
#pragma unroll
      for (int je = 0; je < 4; ++je)
#pragma unroll
        for (int kk = 0; kk < 2; ++kk)
          o[fm][je] = __builtin_amdgcn_mfma_f32_16x16x32_bf16(pf[fm][kk], vf[je][kk], o[fm][je], 0, 0, 0);
  }

  // epilogue: normalize (broadcast 1/l to o rows), stage, coalesced write
#pragma unroll
  for (int fm = 0; fm < 2; ++fm) {
    const float il = 1.0f / l_run[fm];
#pragma unroll
    for (int r = 0; r < 4; ++r) {
      const float iq = __shfl(il, g * 20 + r);
#pragma unroll
      for (int je = 0; je < 4; ++je)
        sP[w * 32 + fm * 16 + g * 4 + r][je * 16 + lr] = f2bf(o[fm][je][r] * iq);
    }
  }
  __syncthreads();
  const int orow = tid >> 1, oc = (tid & 1) * 32;
  unsigned short* dst = &rep[(size_t)(b * 1024 + q0 + orow) * 768 + h * 64 + oc];
#pragma unroll
  for (int i = 0; i < 4; ++i)
    *(short8*)(dst + i * 8) = *(const short8*)&sP[orow][oc + i * 8];
}

// ---------------------------------------------------------------------------
extern "C" void kernel_launch(void* const* d_in, const int* in_sizes, int n_in,
                              void* d_out, int out_size, void* d_ws, size_t ws_size,
                              hipStream_t stream) {
  const float* target = (const float*)d_in[0];
  const float* source = (const float*)d_in[1];
  const float* value  = (const float*)d_in[2];
  const float* Wq = (const float*)d_in[3];
  const float* bq = (const float*)d_in[4];
  const float* Wk = (const float*)d_in[5];
  const float* bk = (const float*)d_in[6];
  const float* Wv = (const float*)d_in[7];
  const float* bv = (const float*)d_in[8];
  const float* Wo = (const float*)d_in[9];
  const float* bo = (const float*)d_in[10];
  float* out = (float*)d_out;

  // persistent (live across attn/oproj) scratch in d_ws (34.6 MB)
  char* ws = (char*)d_ws;
  unsigned short* qb   = (unsigned short*)(ws);                 // [8192][768] bf16
  unsigned short* kb   = (unsigned short*)(ws + 12582912);      // [1024][768] bf16
  unsigned short* vtb  = (unsigned short*)(ws + 14155776);      // [768][1024] bf16 (V^T)
  unsigned short* repb = (unsigned short*)(ws + 15728640);      // [8192][768] bf16
  unsigned short* wob  = (unsigned short*)(ws + 28311552);      // [4096][768] bf16

  // transient scratch inside d_out (134 MB; all consumed before oproj writes)
  char* ob = (char*)d_out;
  unsigned short* targetb = (unsigned short*)(ob);              // 12.58 MB
  unsigned short* sourceb = (unsigned short*)(ob + 12582912);   //  8.19 MB
  unsigned short* valueb  = (unsigned short*)(ob + 20774912);   //  8.19 MB
  unsigned short* wqb     = (unsigned short*)(ob + 28966912);   //  1.18 MB
  unsigned short* wkb     = (unsigned short*)(ob + 30146560);   //  6.29 MB
  unsigned short* wvb     = (unsigned short*)(ob + 36438016);   //  6.29 MB
  float* parts            = (float*)(ob + 42729472);            // 8 x [1024][768] f32

  cvt_all<<<11968, 256, 0, stream>>>(target, source, value, Wq, Wk, Wv, Wo,
                                     targetb, sourceb, valueb, wqb, wkb, wvb, wob);
  qproj_kernel<<<dim3(128, 6), 256, 0, stream>>>(targetb, wqb, bq, qb);
  kvproj_kernel<<<dim3(16, 6, 8), 256, 0, stream>>>(sourceb, valueb, wkb, wvb, parts);
  finalize_kv<<<dim3(384, 1, 2), 256, 0, stream>>>(parts, bk, bv, kb, vtb);
  attn_kernel<<<dim3(8, 96), 256, 0, stream>>>(qb, kb, vtb, repb);
  oproj_kernel<<<dim3(64, 32), 256, 0, stream>>>(repb, wob, bo, out);
}

// Round 7
// 418.548 us; speedup vs baseline: 1.3160x; 1.0709x over previous
//
#include <hip/hip_runtime.h>

typedef __attribute__((ext_vector_type(8))) short short8;
typedef __attribute__((ext_vector_type(4))) float f32x4;
typedef __attribute__((ext_vector_type(2))) unsigned u32x2;

#define DEVI __device__ __forceinline__

// fp32 -> bf16 round-to-nearest-even
DEVI unsigned short f2bf(float x) {
  unsigned u = __builtin_bit_cast(unsigned, x);
  u += 0x7fff + ((u >> 16) & 1u);
  return (unsigned short)(u >> 16);
}

// pack two fp32 -> bf16x2 word (lo = a, hi = b) — single HW op
DEVI unsigned cvtpk(float a, float b) {
  unsigned r;
  asm("v_cvt_pk_bf16_f32 %0, %1, %2" : "=v"(r) : "v"(a), "v"(b));
  return r;
}

// XOR-swizzled LDS address for [rows][64] bf16 tiles (128 B row stride):
// byte = row*128 + (colbyte ^ ((row&7)<<4)). Spreads column slices across
// banks; every fragment access pattern here lands <=2 lanes/bank.
DEVI unsigned short* swz(unsigned short* base, int row, int colb) {
  return (unsigned short*)((char*)base + row * 128 + (colb ^ ((row & 7) << 4)));
}
DEVI const unsigned short* swzc(const unsigned short* base, int row, int colb) {
  return (const unsigned short*)((const char*)base + row * 128 + (colb ^ ((row & 7) << 4)));
}

// ---------------------------------------------------------------------------
// One-pass fp32 -> bf16 conversion of all GEMM inputs (7 tensors).
// ---------------------------------------------------------------------------
__global__ __launch_bounds__(256) void cvt_all(
    const float* __restrict__ t0, const float* __restrict__ t1,
    const float* __restrict__ t2, const float* __restrict__ t3,
    const float* __restrict__ t4, const float* __restrict__ t5,
    const float* __restrict__ t6,
    unsigned short* __restrict__ o0, unsigned short* __restrict__ o1,
    unsigned short* __restrict__ o2, unsigned short* __restrict__ o3,
    unsigned short* __restrict__ o4, unsigned short* __restrict__ o5,
    unsigned short* __restrict__ o6) {
  const unsigned gid = blockIdx.x * 256 + threadIdx.x;
  const float* src;
  unsigned short* dst;
  unsigned base;
  if (gid < 786432u)       { src = t0; dst = o0; base = 0u; }
  else if (gid < 1298432u) { src = t1; dst = o1; base = 786432u; }
  else if (gid < 1810432u) { src = t2; dst = o2; base = 1298432u; }
  else if (gid < 1884160u) { src = t3; dst = o3; base = 1810432u; }
  else if (gid < 2277376u) { src = t4; dst = o4; base = 1884160u; }
  else if (gid < 2670592u) { src = t5; dst = o5; base = 2277376u; }
  else                     { src = t6; dst = o6; base = 2670592u; }
  const size_t i = (size_t)(gid - base) * 8;
  f32x4 a = *(const f32x4*)(src + i);
  f32x4 b = *(const f32x4*)(src + i + 4);
  short8 p;
#pragma unroll
  for (int j = 0; j < 4; ++j) p[j] = (short)f2bf(a[j]);
#pragma unroll
  for (int j = 0; j < 4; ++j) p[j + 4] = (short)f2bf(b[j]);
  *(short8*)&dst[i] = p;
}

// ---------------------------------------------------------------------------
// m97-style bf16 GEMM: C[m,n] = sum_k A[m,k] * B[n,k], global_load_lds w=16.
// (unchanged from round 4 — frozen so next profile isolates GEMM costs)
// ---------------------------------------------------------------------------
template <int TM, int MODE>
DEVI void gemm_body(const unsigned short* __restrict__ A,
                    const unsigned short* __restrict__ B,
                    const float* __restrict__ bias, void* __restrict__ outp,
                    int M, int lda, int ldo, float scale,
                    int bm, int bn, int kbeg, int kend) {
  constexpr int WM = TM / 32;
  constexpr int ROWS = TM + 128;
  constexpr int NCH = ROWS / 16;
  constexpr int CPW = NCH / 4;
  __shared__ unsigned short sAB[ROWS * 32];
  const int tid = threadIdx.x;
  const int lane = tid & 63, wid = tid >> 6;
  const int wr = (wid >> 1) * (WM * 16), wc = (wid & 1) * 64;
  const int m0 = bm * TM, n0 = bn * 128;
  const int grow = lane >> 2, gcol = (lane & 3) * 8;
  const int lr = lane & 15, lk = (lane >> 4) * 8;

  f32x4 acc[WM][4];
#pragma unroll
  for (int i = 0; i < WM; ++i)
#pragma unroll
    for (int j = 0; j < 4; ++j) acc[i][j] = (f32x4){0.f, 0.f, 0.f, 0.f};

  for (int k0 = kbeg; k0 < kend; k0 += 32) {
#pragma unroll
    for (int i = 0; i < CPW; ++i) {
      const int c = wid * CPW + i;
      const int row = c * 16 + grow;
      const unsigned short* src;
      if (c * 16 < TM) {
        int rg = m0 + row;
        if (rg > M - 1) rg = M - 1;
        src = A + (size_t)rg * lda + k0 + gcol;
      } else {
        src = B + (size_t)(n0 + row - TM) * lda + k0 + gcol;
      }
      __builtin_amdgcn_global_load_lds(
          (const __attribute__((address_space(1))) unsigned int*)src,
          (__attribute__((address_space(3))) unsigned int*)(sAB + c * 512),
          16, 0, 0);
    }
    __syncthreads();
    short8 af[WM], bfr[4];
#pragma unroll
    for (int i = 0; i < WM; ++i) af[i]  = *(const short8*)&sAB[(wr + i * 16 + lr) * 32 + lk];
#pragma unroll
    for (int j = 0; j < 4; ++j)  bfr[j] = *(const short8*)&sAB[(TM + wc + j * 16 + lr) * 32 + lk];
#pragma unroll
    for (int i = 0; i < WM; ++i)
#pragma unroll
      for (int j = 0; j < 4; ++j)
        acc[i][j] = __builtin_amdgcn_mfma_f32_16x16x32_bf16(af[i], bfr[j], acc[i][j], 0, 0, 0);
    __syncthreads();
  }

#pragma unroll
  for (int i = 0; i < WM; ++i) {
#pragma unroll
    for (int j = 0; j < 4; ++j) {
      const int n  = n0 + wc + j * 16 + lr;
      const int mb = m0 + wr + i * 16 + (lane >> 4) * 4;
      if (MODE == 0) {
        const float bv = bias[n];
        unsigned short* out = (unsigned short*)outp;
#pragma unroll
        for (int r = 0; r < 4; ++r)
          out[(size_t)(mb + r) * ldo + n] = f2bf((acc[i][j][r] + bv) * scale);
      } else if (MODE == 1) {
        const float bv = bias[n];
        float* out = (float*)outp;
#pragma unroll
        for (int r = 0; r < 4; ++r)
          out[(size_t)(mb + r) * ldo + n] = acc[i][j][r] + bv;
      } else {
        float* out = (float*)outp;
#pragma unroll
        for (int r = 0; r < 4; ++r)
          out[(size_t)(mb + r) * ldo + n] = acc[i][j][r];
      }
    }
  }
}

// Q projection: (8192x768)@Wq^T + bq, scale = 1/8 * log2(e)  (exp2 softmax)
__global__ __launch_bounds__(256) void qproj_kernel(const unsigned short* __restrict__ A,
                                                    const unsigned short* __restrict__ B,
                                                    const float* __restrict__ bq,
                                                    unsigned short* __restrict__ qb) {
  gemm_body<64, 0>(A, B, bq, qb, 8192, 768, 768, 0.18033688011112042f,
                   blockIdx.x, blockIdx.y, 0, 768);
}

// K/V projections, split-K x4 into separate partial buffers (no atomics).
__global__ __launch_bounds__(256) void kvproj_kernel(const unsigned short* __restrict__ sb,
                                                     const unsigned short* __restrict__ vb,
                                                     const unsigned short* __restrict__ wkb,
                                                     const unsigned short* __restrict__ wvb,
                                                     float* __restrict__ parts) {
  const int mat = blockIdx.z >> 2, ks = blockIdx.z & 3;
  const unsigned short* A = mat ? vb : sb;
  const unsigned short* B = mat ? wvb : wkb;
  float* out = parts + (size_t)blockIdx.z * 786432;
  gemm_body<64, 2>(A, B, nullptr, out, 1000, 4096, 768, 1.0f,
                   blockIdx.x, blockIdx.y, ks * 1024, ks * 1024 + 1024);
}

// Output projection: out[8192,4096] = rep@Wo^T + bo
__global__ __launch_bounds__(256) void oproj_kernel(const unsigned short* __restrict__ A,
                                                    const unsigned short* __restrict__ B,
                                                    const float* __restrict__ bo,
                                                    float* __restrict__ out) {
  gemm_body<128, 1>(A, B, bo, out, 8192, 768, 4096, 1.0f,
                    blockIdx.x, blockIdx.y, 0, 768);
}

// finalize split-K partials -> kb[s][n], vtb[n][s]
__global__ __launch_bounds__(256) void finalize_kv(const float* __restrict__ parts,
                                                   const float* __restrict__ bk,
                                                   const float* __restrict__ bv,
                                                   unsigned short* __restrict__ kb,
                                                   unsigned short* __restrict__ vtb) {
  if (blockIdx.z == 0) {
    const int i = (blockIdx.x * 256 + threadIdx.x) * 8;
    const int col = i % 768;
    f32x4 sa = (f32x4){0.f, 0.f, 0.f, 0.f}, sb = sa;
#pragma unroll
    for (int p = 0; p < 4; ++p) {
      sa += *(const f32x4*)(parts + (size_t)p * 786432 + i);
      sb += *(const f32x4*)(parts + (size_t)p * 786432 + i + 4);
    }
    short8 o;
#pragma unroll
    for (int j = 0; j < 4; ++j) o[j] = (short)f2bf(sa[j] + bk[col + j]);
#pragma unroll
    for (int j = 0; j < 4; ++j) o[j + 4] = (short)f2bf(sb[j] + bk[col + 4 + j]);
    *(short8*)&kb[i] = o;
  } else {
    const int idx = blockIdx.x * 256 + threadIdx.x;
    const int n = idx >> 7;
    const int s0 = (idx & 127) * 8;
    const float bvn = bv[n];
    short8 o;
#pragma unroll
    for (int j = 0; j < 8; ++j) {
      float s = 0.f;
#pragma unroll
      for (int p = 0; p < 4; ++p)
        s += parts[(size_t)(4 + p) * 786432 + (size_t)(s0 + j) * 768 + n];
      o[j] = (short)f2bf(s + bvn);
    }
    *(short8*)&vtb[(size_t)n * 1024 + s0] = o;
  }
}

// ---------------------------------------------------------------------------
// Flash cross-attention v3. Grid (L/64, B*H), 4 waves x 16 q-rows.
// Swapped QK^T (lane owns q-row lr), XOR-swizzled LDS (no padding),
// defer-max (THR=8 log2-units), cvt_pk P-pack, exp2 domain.
// ---------------------------------------------------------------------------
__global__ __launch_bounds__(256, 4) void attn_kernel(const unsigned short* __restrict__ q,
                                                      const unsigned short* __restrict__ k,
                                                      const unsigned short* __restrict__ vt,
                                                      unsigned short* __restrict__ rep) {
  __shared__ unsigned short sK[64 * 64];
  __shared__ unsigned short sV[64 * 64];
  __shared__ unsigned short sP[64 * 64];

  const int tid = threadIdx.x;
  const int lane = tid & 63, w = tid >> 6;
  const int g = lane >> 4, lr = lane & 15;
  const int q0 = blockIdx.x * 64;
  const int b = blockIdx.y / 12, h = blockIdx.y % 12;
  const int qrow = b * 1024 + q0 + w * 16 + lr;

  short8 qf[2];
#pragma unroll
  for (int kk = 0; kk < 2; ++kk)
    qf[kk] = *(const short8*)&q[(size_t)qrow * 768 + h * 64 + kk * 32 + g * 8];

  float m_run = -1e30f, l_run = 0.f;
  f32x4 o[4];
#pragma unroll
  for (int je = 0; je < 4; ++je) o[je] = (f32x4){0.f, 0.f, 0.f, 0.f};

  const int strow = tid >> 2;           // 0..63
  const int stcb = (tid & 3) * 32;      // byte col 0,32,64,96

  for (int t = 0; t < 16; ++t) {
    const int s0 = t * 64;
    __syncthreads();
    {  // stage K [s][e] and V^T [e][s], swizzled
      const unsigned short* ks = &k[(size_t)(s0 + strow) * 768 + h * 64 + (tid & 3) * 16];
      *(short8*)swz(sK, strow, stcb)      = *(const short8*)ks;
      *(short8*)swz(sK, strow, stcb + 16) = *(const short8*)(ks + 8);
      const unsigned short* vs = &vt[(size_t)(h * 64 + strow) * 1024 + s0 + (tid & 3) * 16];
      *(short8*)swz(sV, strow, stcb)      = *(const short8*)vs;
      *(short8*)swz(sV, strow, stcb + 16) = *(const short8*)(vs + 8);
    }
    __syncthreads();

    // QK^T swapped: sc[j] = D[s = j*16 + g*4 + r][q = lr]
    f32x4 sc[4];
#pragma unroll
    for (int j = 0; j < 4; ++j) sc[j] = (f32x4){0.f, 0.f, 0.f, 0.f};
#pragma unroll
    for (int j = 0; j < 4; ++j) {
#pragma unroll
      for (int kk = 0; kk < 2; ++kk) {
        const short8 kf = *(const short8*)swzc(sK, j * 16 + lr, kk * 64 + g * 16);
        sc[j] = __builtin_amdgcn_mfma_f32_16x16x32_bf16(kf, qf[kk], sc[j], 0, 0, 0);
      }
    }

    // tail mask: s = s0 + j*16 + g*4 + r
    if (s0 + 64 > 1000) {
#pragma unroll
      for (int j = 0; j < 4; ++j)
#pragma unroll
        for (int r = 0; r < 4; ++r)
          if (s0 + j * 16 + g * 4 + r >= 1000) sc[j][r] = -1e30f;
    }

    // online softmax, defer-max: skip rescale while tile max stays within 8
    float mx = -1e30f;
#pragma unroll
    for (int j = 0; j < 4; ++j)
      mx = fmaxf(mx, fmaxf(fmaxf(sc[j][0], sc[j][1]), fmaxf(sc[j][2], sc[j][3])));
    mx = fmaxf(mx, __shfl_xor(mx, 16));
    mx = fmaxf(mx, __shfl_xor(mx, 32));
    if (!__all(mx <= m_run + 8.0f)) {
      const float mnew = fmaxf(m_run, mx);
      const float fac = exp2f(m_run - mnew);
      m_run = mnew;
      l_run *= fac;
#pragma unroll
      for (int r = 0; r < 4; ++r) {
        const float fq = __shfl(fac, g * 20 + r);
#pragma unroll
        for (int je = 0; je < 4; ++je) o[je][r] *= fq;
      }
    }
    float rs = 0.f;
#pragma unroll
    for (int j = 0; j < 4; ++j)
#pragma unroll
      for (int r = 0; r < 4; ++r) {
        const float p = exp2f(sc[j][r] - m_run);
        sc[j][r] = p;
        rs += p;
      }
    rs += __shfl_xor(rs, 16);
    rs += __shfl_xor(rs, 32);
    l_run += rs;

    // P -> LDS (swizzled b64 writes; wave-private rows; DS in-order per wave)
#pragma unroll
    for (int j = 0; j < 4; ++j) {
      u32x2 pw;
      pw[0] = cvtpk(sc[j][0], sc[j][1]);
      pw[1] = cvtpk(sc[j][2], sc[j][3]);
      *(u32x2*)swz(sP, w * 16 + lr, j * 32 + g * 8) = pw;
    }
    asm volatile("s_waitcnt lgkmcnt(0)" ::: "memory");

    // PV: o += P(16x64) @ V(64x64)
    short8 pf[2];
#pragma unroll
    for (int kk = 0; kk < 2; ++kk)
      pf[kk] = *(const short8*)swzc(sP, w * 16 + lr, kk * 64 + g * 16);
#pragma unroll
    for (int je = 0; je < 4; ++je) {
#pragma unroll
      for (int kk = 0; kk < 2; ++kk) {
        const short8 vf = *(const short8*)swzc(sV, je * 16 + lr, kk * 64 + g * 16);
        o[je] = __builtin_amdgcn_mfma_f32_16x16x32_bf16(pf[kk], vf, o[je], 0, 0, 0);
      }
    }
  }

  // epilogue: normalize, stage (swizzled), coalesced bf16 write
  const float il = 1.0f / l_run;
#pragma unroll
  for (int r = 0; r < 4; ++r) {
    const float iq = __shfl(il, g * 20 + r);
#pragma unroll
    for (int je = 0; je < 4; ++je)
      *swz(sP, w * 16 + g * 4 + r, (je * 16 + lr) * 2) = f2bf(o[je][r] * iq);
  }
  __syncthreads();
  const int orow = tid >> 2, ocb = (tid & 3) * 32;
  unsigned short* dst = &rep[(size_t)(b * 1024 + q0 + orow) * 768 + h * 64 + (tid & 3) * 16];
  *(short8*)dst       = *(const short8*)swzc(sP, orow, ocb);
  *(short8*)(dst + 8) = *(const short8*)swzc(sP, orow, ocb + 16);
}

// ---------------------------------------------------------------------------
extern "C" void kernel_launch(void* const* d_in, const int* in_sizes, int n_in,
                              void* d_out, int out_size, void* d_ws, size_t ws_size,
                              hipStream_t stream) {
  const float* target = (const float*)d_in[0];
  const float* source = (const float*)d_in[1];
  const float* value  = (const float*)d_in[2];
  const float* Wq = (const float*)d_in[3];
  const float* bq = (const float*)d_in[4];
  const float* Wk = (const float*)d_in[5];
  const float* bk = (const float*)d_in[6];
  const float* Wv = (const float*)d_in[7];
  const float* bv = (const float*)d_in[8];
  const float* Wo = (const float*)d_in[9];
  const float* bo = (const float*)d_in[10];
  float* out = (float*)d_out;

  // persistent (live across attn/oproj) scratch in d_ws (34.6 MB)
  char* ws = (char*)d_ws;
  unsigned short* qb   = (unsigned short*)(ws);                 // [8192][768] bf16
  unsigned short* kb   = (unsigned short*)(ws + 12582912);      // [1024][768] bf16
  unsigned short* vtb  = (unsigned short*)(ws + 14155776);      // [768][1024] bf16 (V^T)
  unsigned short* repb = (unsigned short*)(ws + 15728640);      // [8192][768] bf16
  unsigned short* wob  = (unsigned short*)(ws + 28311552);      // [4096][768] bf16

  // transient scratch inside d_out (134 MB; all consumed before oproj writes)
  char* ob = (char*)d_out;
  unsigned short* targetb = (unsigned short*)(ob);              // 12.58 MB
  unsigned short* sourceb = (unsigned short*)(ob + 12582912);   //  8.19 MB
  unsigned short* valueb  = (unsigned short*)(ob + 20774912);   //  8.19 MB
  unsigned short* wqb     = (unsigned short*)(ob + 28966912);   //  1.18 MB
  unsigned short* wkb     = (unsigned short*)(ob + 30146560);   //  6.29 MB
  unsigned short* wvb     = (unsigned short*)(ob + 36438016);   //  6.29 MB
  float* parts            = (float*)(ob + 42729472);            // 8 x [1024][768] f32

  cvt_all<<<11968, 256, 0, stream>>>(target, source, value, Wq, Wk, Wv, Wo,
                                     targetb, sourceb, valueb, wqb, wkb, wvb, wob);
  qproj_kernel<<<dim3(128, 6), 256, 0, stream>>>(targetb, wqb, bq, qb);
  kvproj_kernel<<<dim3(16, 6, 8), 256, 0, stream>>>(sourceb, valueb, wkb, wvb, parts);
  finalize_kv<<<dim3(384, 1, 2), 256, 0, stream>>>(parts, bk, bv, kb, vtb);
  attn_kernel<<<dim3(16, 96), 256, 0, stream>>>(qb, kb, vtb, repb);
  oproj_kernel<<<dim3(64, 32), 256, 0, stream>>>(repb, wob, bo, out);
}

// Round 8
// 416.972 us; speedup vs baseline: 1.3210x; 1.0038x over previous
//
#include <hip/hip_runtime.h>

typedef __attribute__((ext_vector_type(8))) short short8;
typedef __attribute__((ext_vector_type(4))) float f32x4;
typedef __attribute__((ext_vector_type(2))) unsigned u32x2;

#define DEVI __device__ __forceinline__

// fp32 -> bf16 round-to-nearest-even
DEVI unsigned short f2bf(float x) {
  unsigned u = __builtin_bit_cast(unsigned, x);
  u += 0x7fff + ((u >> 16) & 1u);
  return (unsigned short)(u >> 16);
}

// pack two fp32 -> bf16x2 word (lo = a, hi = b) — single HW op
DEVI unsigned cvtpk(float a, float b) {
  unsigned r;
  asm("v_cvt_pk_bf16_f32 %0, %1, %2" : "=v"(r) : "v"(a), "v"(b));
  return r;
}

// XOR-swizzled LDS address for [rows][64] bf16 tiles (128 B row stride)
DEVI unsigned short* swz(unsigned short* base, int row, int colb) {
  return (unsigned short*)((char*)base + row * 128 + (colb ^ ((row & 7) << 4)));
}
DEVI const unsigned short* swzc(const unsigned short* base, int row, int colb) {
  return (const unsigned short*)((const char*)base + row * 128 + (colb ^ ((row & 7) << 4)));
}

// ---------------------------------------------------------------------------
// One-pass fp32 -> bf16 conversion of all GEMM inputs (7 tensors).
// ---------------------------------------------------------------------------
__global__ __launch_bounds__(256) void cvt_all(
    const float* __restrict__ t0, const float* __restrict__ t1,
    const float* __restrict__ t2, const float* __restrict__ t3,
    const float* __restrict__ t4, const float* __restrict__ t5,
    const float* __restrict__ t6,
    unsigned short* __restrict__ o0, unsigned short* __restrict__ o1,
    unsigned short* __restrict__ o2, unsigned short* __restrict__ o3,
    unsigned short* __restrict__ o4, unsigned short* __restrict__ o5,
    unsigned short* __restrict__ o6) {
  const unsigned gid = blockIdx.x * 256 + threadIdx.x;
  const float* src;
  unsigned short* dst;
  unsigned base;
  if (gid < 786432u)       { src = t0; dst = o0; base = 0u; }
  else if (gid < 1298432u) { src = t1; dst = o1; base = 786432u; }
  else if (gid < 1810432u) { src = t2; dst = o2; base = 1298432u; }
  else if (gid < 1884160u) { src = t3; dst = o3; base = 1810432u; }
  else if (gid < 2277376u) { src = t4; dst = o4; base = 1884160u; }
  else if (gid < 2670592u) { src = t5; dst = o5; base = 2277376u; }
  else                     { src = t6; dst = o6; base = 2670592u; }
  const size_t i = (size_t)(gid - base) * 8;
  f32x4 a = *(const f32x4*)(src + i);
  f32x4 b = *(const f32x4*)(src + i + 4);
  short8 p;
#pragma unroll
  for (int j = 0; j < 4; ++j) p[j] = (short)f2bf(a[j]);
#pragma unroll
  for (int j = 0; j < 4; ++j) p[j + 4] = (short)f2bf(b[j]);
  *(short8*)&dst[i] = p;
}

// ---------------------------------------------------------------------------
// bf16 GEMM, 2-phase prefetch: double-buffered LDS, STAGE(t+1) issued BEFORE
// compute(t), ONE barrier per K-step (drain covers the prefetch). Source row
// pointers hoisted out of the K-loop. C[m,n] = sum_k A[m,k]*B[n,k].
// MODE 0: bf16 out, (acc+bias)*scale | MODE 1: f32 out, acc+bias
// MODE 2: f32 out, raw acc (split-K partial)
// ---------------------------------------------------------------------------
template <int TM, int MODE>
DEVI void gemm_body(const unsigned short* __restrict__ A,
                    const unsigned short* __restrict__ B,
                    const float* __restrict__ bias, void* __restrict__ outp,
                    int M, int lda, int ldo, float scale,
                    int bm, int bn, int kbeg, int kend) {
  constexpr int WM = TM / 32;
  constexpr int ROWS = TM + 128;       // A rows then B rows
  constexpr int NCH = ROWS / 16;       // 16-row chunks (1 KiB each)
  constexpr int CPW = NCH / 4;
  __shared__ unsigned short sAB[2][ROWS * 32];
  const int tid = threadIdx.x;
  const int lane = tid & 63, wid = tid >> 6;
  const int wr = (wid >> 1) * (WM * 16), wc = (wid & 1) * 64;
  const int m0 = bm * TM, n0 = bn * 128;
  const int grow = lane >> 2, gcol = (lane & 3) * 8;
  const int lr = lane & 15, lk = (lane >> 4) * 8;

  // hoisted per-chunk global base pointers (k advances by += k0)
  const unsigned short* srcs[CPW];
#pragma unroll
  for (int i = 0; i < CPW; ++i) {
    const int c = wid * CPW + i;
    const int row = c * 16 + grow;
    if (c * 16 < TM) {
      int rg = m0 + row;
      if (rg > M - 1) rg = M - 1;      // clamp (finite junk, masked downstream)
      srcs[i] = A + (size_t)rg * lda + gcol;
    } else {
      srcs[i] = B + (size_t)(n0 + row - TM) * lda + gcol;
    }
  }

  f32x4 acc[WM][4];
#pragma unroll
  for (int i = 0; i < WM; ++i)
#pragma unroll
    for (int j = 0; j < 4; ++j) acc[i][j] = (f32x4){0.f, 0.f, 0.f, 0.f};

#define STAGE(bi, k0)                                                          \
  {                                                                            \
    _Pragma("unroll") for (int i = 0; i < CPW; ++i) {                          \
      const int c = wid * CPW + i;                                             \
      __builtin_amdgcn_global_load_lds(                                        \
          (const __attribute__((address_space(1))) unsigned int*)(srcs[i] + (k0)), \
          (__attribute__((address_space(3))) unsigned int*)(&sAB[bi][0] + c * 512), \
          16, 0, 0);                                                           \
    }                                                                          \
  }

  STAGE(0, kbeg);
  __syncthreads();                     // drain prologue loads
  int buf = 0;
  for (int k0 = kbeg; k0 < kend; k0 += 32) {
    if (k0 + 32 < kend) STAGE(buf ^ 1, k0 + 32);   // prefetch overlaps MFMA
    const unsigned short* sb = &sAB[buf][0];
    short8 af[WM], bfr[4];
#pragma unroll
    for (int i = 0; i < WM; ++i) af[i]  = *(const short8*)&sb[(wr + i * 16 + lr) * 32 + lk];
#pragma unroll
    for (int j = 0; j < 4; ++j)  bfr[j] = *(const short8*)&sb[(TM + wc + j * 16 + lr) * 32 + lk];
#pragma unroll
    for (int i = 0; i < WM; ++i)
#pragma unroll
      for (int j = 0; j < 4; ++j)
        acc[i][j] = __builtin_amdgcn_mfma_f32_16x16x32_bf16(af[i], bfr[j], acc[i][j], 0, 0, 0);
    __syncthreads();                   // one barrier/K-step: drains prefetch,
    buf ^= 1;                          // protects buf reuse next iteration
  }
#undef STAGE

  // C-write. C/D layout: col = lane&15, row = (lane>>4)*4 + r
#pragma unroll
  for (int i = 0; i < WM; ++i) {
#pragma unroll
    for (int j = 0; j < 4; ++j) {
      const int n  = n0 + wc + j * 16 + lr;
      const int mb = m0 + wr + i * 16 + (lane >> 4) * 4;
      if (MODE == 0) {
        const float bv = bias[n];
        unsigned short* out = (unsigned short*)outp;
#pragma unroll
        for (int r = 0; r < 4; ++r)
          out[(size_t)(mb + r) * ldo + n] = f2bf((acc[i][j][r] + bv) * scale);
      } else if (MODE == 1) {
        const float bv = bias[n];
        float* out = (float*)outp;
#pragma unroll
        for (int r = 0; r < 4; ++r)
          out[(size_t)(mb + r) * ldo + n] = acc[i][j][r] + bv;
      } else {
        float* out = (float*)outp;
#pragma unroll
        for (int r = 0; r < 4; ++r)
          out[(size_t)(mb + r) * ldo + n] = acc[i][j][r];
      }
    }
  }
}

// Q projection: (8192x768)@Wq^T + bq, scale = 1/8 * log2(e)  (exp2 softmax)
__global__ __launch_bounds__(256) void qproj_kernel(const unsigned short* __restrict__ A,
                                                    const unsigned short* __restrict__ B,
                                                    const float* __restrict__ bq,
                                                    unsigned short* __restrict__ qb) {
  gemm_body<64, 0>(A, B, bq, qb, 8192, 768, 768, 0.18033688011112042f,
                   blockIdx.x, blockIdx.y, 0, 768);
}

// K/V projections, split-K x4 into separate partial buffers (no atomics).
__global__ __launch_bounds__(256) void kvproj_kernel(const unsigned short* __restrict__ sb,
                                                     const unsigned short* __restrict__ vb,
                                                     const unsigned short* __restrict__ wkb,
                                                     const unsigned short* __restrict__ wvb,
                                                     float* __restrict__ parts) {
  const int mat = blockIdx.z >> 2, ks = blockIdx.z & 3;
  const unsigned short* A = mat ? vb : sb;
  const unsigned short* B = mat ? wvb : wkb;
  float* out = parts + (size_t)blockIdx.z * 786432;
  gemm_body<64, 2>(A, B, nullptr, out, 1000, 4096, 768, 1.0f,
                   blockIdx.x, blockIdx.y, ks * 1024, ks * 1024 + 1024);
}

// Output projection: out[8192,4096] = rep@Wo^T + bo
__global__ __launch_bounds__(256) void oproj_kernel(const unsigned short* __restrict__ A,
                                                    const unsigned short* __restrict__ B,
                                                    const float* __restrict__ bo,
                                                    float* __restrict__ out) {
  gemm_body<128, 1>(A, B, bo, out, 8192, 768, 4096, 1.0f,
                    blockIdx.x, blockIdx.y, 0, 768);
}

// finalize split-K partials -> kb[s][n], vtb[n][s]
__global__ __launch_bounds__(256) void finalize_kv(const float* __restrict__ parts,
                                                   const float* __restrict__ bk,
                                                   const float* __restrict__ bv,
                                                   unsigned short* __restrict__ kb,
                                                   unsigned short* __restrict__ vtb) {
  if (blockIdx.z == 0) {
    const int i = (blockIdx.x * 256 + threadIdx.x) * 8;
    const int col = i % 768;
    f32x4 sa = (f32x4){0.f, 0.f, 0.f, 0.f}, sb = sa;
#pragma unroll
    for (int p = 0; p < 4; ++p) {
      sa += *(const f32x4*)(parts + (size_t)p * 786432 + i);
      sb += *(const f32x4*)(parts + (size_t)p * 786432 + i + 4);
    }
    short8 o;
#pragma unroll
    for (int j = 0; j < 4; ++j) o[j] = (short)f2bf(sa[j] + bk[col + j]);
#pragma unroll
    for (int j = 0; j < 4; ++j) o[j + 4] = (short)f2bf(sb[j] + bk[col + 4 + j]);
    *(short8*)&kb[i] = o;
  } else {
    const int idx = blockIdx.x * 256 + threadIdx.x;
    const int n = idx >> 7;
    const int s0 = (idx & 127) * 8;
    const float bvn = bv[n];
    short8 o;
#pragma unroll
    for (int j = 0; j < 8; ++j) {
      float s = 0.f;
#pragma unroll
      for (int p = 0; p < 4; ++p)
        s += parts[(size_t)(4 + p) * 786432 + (size_t)(s0 + j) * 768 + n];
      o[j] = (short)f2bf(s + bvn);
    }
    *(short8*)&vtb[(size_t)n * 1024 + s0] = o;
  }
}

// ---------------------------------------------------------------------------
// Flash cross-attention v3 (unchanged from round 7 — frozen for attribution).
// Grid (L/64, B*H), 4 waves x 16 q-rows. Swapped QK^T, XOR-swizzled LDS,
// defer-max (THR=8 log2-units), cvt_pk P-pack, exp2 domain.
// ---------------------------------------------------------------------------
__global__ __launch_bounds__(256, 4) void attn_kernel(const unsigned short* __restrict__ q,
                                                      const unsigned short* __restrict__ k,
                                                      const unsigned short* __restrict__ vt,
                                                      unsigned short* __restrict__ rep) {
  __shared__ unsigned short sK[64 * 64];
  __shared__ unsigned short sV[64 * 64];
  __shared__ unsigned short sP[64 * 64];

  const int tid = threadIdx.x;
  const int lane = tid & 63, w = tid >> 6;
  const int g = lane >> 4, lr = lane & 15;
  const int q0 = blockIdx.x * 64;
  const int b = blockIdx.y / 12, h = blockIdx.y % 12;
  const int qrow = b * 1024 + q0 + w * 16 + lr;

  short8 qf[2];
#pragma unroll
  for (int kk = 0; kk < 2; ++kk)
    qf[kk] = *(const short8*)&q[(size_t)qrow * 768 + h * 64 + kk * 32 + g * 8];

  float m_run = -1e30f, l_run = 0.f;
  f32x4 o[4];
#pragma unroll
  for (int je = 0; je < 4; ++je) o[je] = (f32x4){0.f, 0.f, 0.f, 0.f};

  const int strow = tid >> 2;           // 0..63
  const int stcb = (tid & 3) * 32;      // byte col 0,32,64,96

  for (int t = 0; t < 16; ++t) {
    const int s0 = t * 64;
    __syncthreads();
    {  // stage K [s][e] and V^T [e][s], swizzled
      const unsigned short* ks = &k[(size_t)(s0 + strow) * 768 + h * 64 + (tid & 3) * 16];
      *(short8*)swz(sK, strow, stcb)      = *(const short8*)ks;
      *(short8*)swz(sK, strow, stcb + 16) = *(const short8*)(ks + 8);
      const unsigned short* vs = &vt[(size_t)(h * 64 + strow) * 1024 + s0 + (tid & 3) * 16];
      *(short8*)swz(sV, strow, stcb)      = *(const short8*)vs;
      *(short8*)swz(sV, strow, stcb + 16) = *(const short8*)(vs + 8);
    }
    __syncthreads();

    // QK^T swapped: sc[j] = D[s = j*16 + g*4 + r][q = lr]
    f32x4 sc[4];
#pragma unroll
    for (int j = 0; j < 4; ++j) sc[j] = (f32x4){0.f, 0.f, 0.f, 0.f};
#pragma unroll
    for (int j = 0; j < 4; ++j) {
#pragma unroll
      for (int kk = 0; kk < 2; ++kk) {
        const short8 kf = *(const short8*)swzc(sK, j * 16 + lr, kk * 64 + g * 16);
        sc[j] = __builtin_amdgcn_mfma_f32_16x16x32_bf16(kf, qf[kk], sc[j], 0, 0, 0);
      }
    }

    // tail mask: s = s0 + j*16 + g*4 + r
    if (s0 + 64 > 1000) {
#pragma unroll
      for (int j = 0; j < 4; ++j)
#pragma unroll
        for (int r = 0; r < 4; ++r)
          if (s0 + j * 16 + g * 4 + r >= 1000) sc[j][r] = -1e30f;
    }

    // online softmax, defer-max: skip rescale while tile max stays within 8
    float mx = -1e30f;
#pragma unroll
    for (int j = 0; j < 4; ++j)
      mx = fmaxf(mx, fmaxf(fmaxf(sc[j][0], sc[j][1]), fmaxf(sc[j][2], sc[j][3])));
    mx = fmaxf(mx, __shfl_xor(mx, 16));
    mx = fmaxf(mx, __shfl_xor(mx, 32));
    if (!__all(mx <= m_run + 8.0f)) {
      const float mnew = fmaxf(m_run, mx);
      const float fac = exp2f(m_run - mnew);
      m_run = mnew;
      l_run *= fac;
#pragma unroll
      for (int r = 0; r < 4; ++r) {
        const float fq = __shfl(fac, g * 20 + r);
#pragma unroll
        for (int je = 0; je < 4; ++je) o[je][r] *= fq;
      }
    }
    float rs = 0.f;
#pragma unroll
    for (int j = 0; j < 4; ++j)
#pragma unroll
      for (int r = 0; r < 4; ++r) {
        const float p = exp2f(sc[j][r] - m_run);
        sc[j][r] = p;
        rs += p;
      }
    rs += __shfl_xor(rs, 16);
    rs += __shfl_xor(rs, 32);
    l_run += rs;

    // P -> LDS (swizzled b64 writes; wave-private rows; DS in-order per wave)
#pragma unroll
    for (int j = 0; j < 4; ++j) {
      u32x2 pw;
      pw[0] = cvtpk(sc[j][0], sc[j][1]);
      pw[1] = cvtpk(sc[j][2], sc[j][3]);
      *(u32x2*)swz(sP, w * 16 + lr, j * 32 + g * 8) = pw;
    }
    asm volatile("s_waitcnt lgkmcnt(0)" ::: "memory");

    // PV: o += P(16x64) @ V(64x64)
    short8 pf[2];
#pragma unroll
    for (int kk = 0; kk < 2; ++kk)
      pf[kk] = *(const short8*)swzc(sP, w * 16 + lr, kk * 64 + g * 16);
#pragma unroll
    for (int je = 0; je < 4; ++je) {
#pragma unroll
      for (int kk = 0; kk < 2; ++kk) {
        const short8 vf = *(const short8*)swzc(sV, je * 16 + lr, kk * 64 + g * 16);
        o[je] = __builtin_amdgcn_mfma_f32_16x16x32_bf16(pf[kk], vf, o[je], 0, 0, 0);
      }
    }
  }

  // epilogue: normalize, stage (swizzled), coalesced bf16 write
  const float il = 1.0f / l_run;
#pragma unroll
  for (int r = 0; r < 4; ++r) {
    const float iq = __shfl(il, g * 20 + r);
#pragma unroll
    for (int je = 0; je < 4; ++je)
      *swz(sP, w * 16 + g * 4 + r, (je * 16 + lr) * 2) = f2bf(o[je][r] * iq);
  }
  __syncthreads();
  const int orow = tid >> 2, ocb = (tid & 3) * 32;
  unsigned short* dst = &rep[(size_t)(b * 1024 + q0 + orow) * 768 + h * 64 + (tid & 3) * 16];
  *(short8*)dst       = *(const short8*)swzc(sP, orow, ocb);
  *(short8*)(dst + 8) = *(const short8*)swzc(sP, orow, ocb + 16);
}

// ---------------------------------------------------------------------------
extern "C" void kernel_launch(void* const* d_in, const int* in_sizes, int n_in,
                              void* d_out, int out_size, void* d_ws, size_t ws_size,
                              hipStream_t stream) {
  const float* target = (const float*)d_in[0];
  const float* source = (const float*)d_in[1];
  const float* value  = (const float*)d_in[2];
  const float* Wq = (const float*)d_in[3];
  const float* bq = (const float*)d_in[4];
  const float* Wk = (const float*)d_in[5];
  const float* bk = (const float*)d_in[6];
  const float* Wv = (const float*)d_in[7];
  const float* bv = (const float*)d_in[8];
  const float* Wo = (const float*)d_in[9];
  const float* bo = (const float*)d_in[10];
  float* out = (float*)d_out;

  // persistent (live across attn/oproj) scratch in d_ws (34.6 MB)
  char* ws = (char*)d_ws;
  unsigned short* qb   = (unsigned short*)(ws);                 // [8192][768] bf16
  unsigned short* kb   = (unsigned short*)(ws + 12582912);      // [1024][768] bf16
  unsigned short* vtb  = (unsigned short*)(ws + 14155776);      // [768][1024] bf16 (V^T)
  unsigned short* repb = (unsigned short*)(ws + 15728640);      // [8192][768] bf16
  unsigned short* wob  = (unsigned short*)(ws + 28311552);      // [4096][768] bf16

  // transient scratch inside d_out (134 MB; all consumed before oproj writes)
  char* ob = (char*)d_out;
  unsigned short* targetb = (unsigned short*)(ob);              // 12.58 MB
  unsigned short* sourceb = (unsigned short*)(ob + 12582912);   //  8.19 MB
  unsigned short* valueb  = (unsigned short*)(ob + 20774912);   //  8.19 MB
  unsigned short* wqb     = (unsigned short*)(ob + 28966912);   //  1.18 MB
  unsigned short* wkb     = (unsigned short*)(ob + 30146560);   //  6.29 MB
  unsigned short* wvb     = (unsigned short*)(ob + 36438016);   //  6.29 MB
  float* parts            = (float*)(ob + 42729472);            // 8 x [1024][768] f32

  cvt_all<<<11968, 256, 0, stream>>>(target, source, value, Wq, Wk, Wv, Wo,
                                     targetb, sourceb, valueb, wqb, wkb, wvb, wob);
  qproj_kernel<<<dim3(128, 6), 256, 0, stream>>>(targetb, wqb, bq, qb);
  kvproj_kernel<<<dim3(16, 6, 8), 256, 0, stream>>>(sourceb, valueb, wkb, wvb, parts);
  finalize_kv<<<dim3(384, 1, 2), 256, 0, stream>>>(parts, bk, bv, kb, vtb);
  attn_kernel<<<dim3(16, 96), 256, 0, stream>>>(qb, kb, vtb, repb);
  oproj_kernel<<<dim3(64, 32), 256, 0, stream>>>(repb, wob, bo, out);
}